// Round 13
// baseline (426.183 us; speedup 1.0000x reference)
//
#include <hip/hip_runtime.h>

// GCN on 1M nodes / 16M edges, collapsed to scalar per-node features.
//
//   deg[c]  = sum_{e: col=c} ew[e] + 1 (self loop)
//   dis     = rsqrt(deg)
//   S1[c]   = dis[c] * (sum_e dis[row]*ew*x[row]) + dis[c]^2 * x[c]
//   g[c]    = sum_j relu(S1[c]*W1[j] + b1[j]) * W2[j]
//   S2[c]   = dis[c] * (sum_e dis[row]*ew*g[row]) + dis[c]^2 * g[c]
//   y[c]    = sigmoid((S2[c]+b2)*Wl + bl)
//
// R12 post-mortem: fill pinned at 108us across occupancy 44->69%; accs
// pinned ~83us across 5 geometries. Binding resource = per-record memory
// ops + bytes. R13: SoA 6B records (PK u32 + W16 bf16) -> acc does 3 loads
// per 8 records (was 4) and streams 96MB not 128MB; CHUNK 6144 halves
// block/hist overheads and doubles write-run length.

constexpr int N_NODES = 1000000;
constexpr int N_EDGES = 16000000;

constexpr int BSHIFT = 12;
constexpr int BNODES = 1 << BSHIFT;                    // 4096 nodes/bucket
constexpr int NB = (N_NODES + BNODES - 1) / BNODES;    // 245 buckets
constexpr int EPT = 12;                                // edges/thread in count+fill
constexpr int FBLK = 512;                              // threads in count+fill
constexpr int CHUNK = FBLK * EPT;                      // 6144 edges/block
constexpr int NBLK = (N_EDGES + CHUNK - 1) / CHUNK;    // 2605
constexpr int NHIST = NB * NBLK;                       // 638,225
constexpr int SCAN_TPB = 256;
constexpr int SCAN_EPB = 1024;
constexpr int NSCAN = (NHIST + SCAN_EPB - 1) / SCAN_EPB;  // 624
constexpr int NHIST_PAD = NSCAN * SCAN_EPB;            // 638,976

__device__ inline unsigned short f2bf(float f) {   // fp32 -> bf16 RNE
  unsigned u = __float_as_uint(f);
  return (unsigned short)((u + 0x7FFFu + ((u >> 16) & 1u)) >> 16);
}
__device__ inline float bf2f(unsigned short h) {
  return __uint_as_float((unsigned)h << 16);
}

// ---------------- build: count / transpose / scan / transpose / fill --------

// histT layout [NBLK][256]: block writes its own contiguous row (coalesced).
__global__ __launch_bounds__(FBLK) void k_count(const int* __restrict__ col,
                                                unsigned* __restrict__ histT) {
  __shared__ unsigned cnt[256];
  int t = threadIdx.x;
  if (t < 256) cnt[t] = 0;
  __syncthreads();
  int e0 = blockIdx.x * CHUNK;
  if (e0 + CHUNK <= N_EDGES) {          // fast path: all loads unguarded
    int c[EPT];
#pragma unroll
    for (int k = 0; k < EPT; ++k) c[k] = col[e0 + k * FBLK + t];
    __builtin_amdgcn_sched_barrier(0);  // keep the load batch issued together
#pragma unroll
    for (int k = 0; k < EPT; ++k) atomicAdd(&cnt[c[k] >> BSHIFT], 1u);
  } else {
#pragma unroll
    for (int k = 0; k < EPT; ++k) {
      int e = e0 + k * FBLK + t;
      if (e < N_EDGES) atomicAdd(&cnt[col[e] >> BSHIFT], 1u);
    }
  }
  __syncthreads();
  if (t < 256) histT[(size_t)blockIdx.x * 256 + t] = cnt[t];
}

// histT[NBLK][256] -> hist[b*NBLK + blk] (bucket-major flat, for linear scan)
__global__ __launch_bounds__(1024) void k_t1(const unsigned* __restrict__ in,
                                             unsigned* __restrict__ out) {
  __shared__ unsigned tile[32][33];
  int bx = blockIdx.x * 32;   // blk base
  int by = blockIdx.y * 32;   // b base
  int tx = threadIdx.x, ty = threadIdx.y;
  int rblk = bx + ty;
  if (rblk < NBLK) tile[ty][tx] = in[(size_t)rblk * 256 + by + tx];
  __syncthreads();
  int wb = by + ty, wblk = bx + tx;
  if (wb < NB && wblk < NBLK) out[(size_t)wb * NBLK + wblk] = tile[tx][ty];
}

// hist offsets (bucket-major) -> histT2[blk*256 + b] (fill reads coalesced)
__global__ __launch_bounds__(1024) void k_t2(const unsigned* __restrict__ in,
                                             unsigned* __restrict__ out) {
  __shared__ unsigned tile[32][33];
  int bx = blockIdx.x * 32;   // blk base
  int by = blockIdx.y * 32;   // b base
  int tx = threadIdx.x, ty = threadIdx.y;
  int rb = by + ty, rblk = bx + tx;
  if (rb < NB && rblk < NBLK) tile[ty][tx] = in[(size_t)rb * NBLK + rblk];
  __syncthreads();
  int wblk = bx + ty, wb = by + tx;
  if (wblk < NBLK && wb < NB) out[(size_t)wblk * 256 + wb] = tile[tx][ty];
}

__global__ __launch_bounds__(SCAN_TPB) void k_scanA(unsigned* __restrict__ h,
                                                    unsigned* __restrict__ bsum) {
  __shared__ unsigned sc[SCAN_TPB];
  int t = threadIdx.x;
  size_t base = (size_t)blockIdx.x * SCAN_EPB + (size_t)t * 4;
  uint4 v = *(const uint4*)(h + base);
  unsigned s = v.x + v.y + v.z + v.w;
  sc[t] = s;
  __syncthreads();
  for (int d = 1; d < SCAN_TPB; d <<= 1) {
    unsigned u = (t >= d) ? sc[t - d] : 0;
    __syncthreads();
    sc[t] += u;
    __syncthreads();
  }
  unsigned ex = sc[t] - s;
  uint4 o;
  o.x = ex; o.y = ex + v.x; o.z = ex + v.x + v.y; o.w = ex + v.x + v.y + v.z;
  *(uint4*)(h + base) = o;
  if (t == SCAN_TPB - 1) bsum[blockIdx.x] = sc[t];
}

__global__ __launch_bounds__(1024) void k_scanB(unsigned* __restrict__ bsum) {
  __shared__ unsigned sc[1024];
  int t = threadIdx.x;
  unsigned a0 = (2 * t < NSCAN) ? bsum[2 * t] : 0;
  unsigned a1 = (2 * t + 1 < NSCAN) ? bsum[2 * t + 1] : 0;
  unsigned s = a0 + a1;
  sc[t] = s;
  __syncthreads();
  for (int d = 1; d < 1024; d <<= 1) {
    unsigned u = (t >= d) ? sc[t - d] : 0;
    __syncthreads();
    sc[t] += u;
    __syncthreads();
  }
  unsigned ex = sc[t] - s;
  if (2 * t < NSCAN) bsum[2 * t] = ex;
  if (2 * t + 1 < NSCAN) bsum[2 * t + 1] = ex + a0;
}

__global__ __launch_bounds__(SCAN_TPB) void k_scanC(unsigned* __restrict__ h,
                                                    const unsigned* __restrict__ bsum) {
  unsigned add = bsum[blockIdx.x];
  size_t base = (size_t)blockIdx.x * SCAN_EPB + (size_t)threadIdx.x * 4;
  uint4 v = *(uint4*)(h + base);
  v.x += add; v.y += add; v.z += add; v.w += add;
  *(uint4*)(h + base) = v;
}

// Register-stash + LDS-reorder fill, SoA output: PK (u32) + W16 (bf16).
// pk = row<<12 | col&0xFFF; row < 2^20 fits.
__global__ __launch_bounds__(FBLK) void k_fill(const int* __restrict__ row,
                                               const int* __restrict__ col,
                                               const float* __restrict__ ew,
                                               const unsigned* __restrict__ histT2,
                                               unsigned* __restrict__ PK,
                                               unsigned short* __restrict__ W16) {
  __shared__ unsigned lhist[FBLK];
  __shared__ unsigned lb[FBLK];
  __shared__ unsigned tail[FBLK];
  __shared__ unsigned gbase[NB];
  __shared__ unsigned wsum[FBLK / 64];
  __shared__ unsigned spk[CHUNK];          // 24KB
  __shared__ unsigned short sw[CHUNK];     // 12KB
  __shared__ unsigned short sbkt[CHUNK];   // 12KB (2B: 2 lanes/bank = free)

  int t = threadIdx.x;
  int blk = blockIdx.x;
  lhist[t] = 0;
  if (t < NB) gbase[t] = histT2[(size_t)blk * 256 + t];  // coalesced row read
  __syncthreads();                                        // B1

  int e0 = blk * CHUNK;
  unsigned pk[EPT];
  unsigned short wv[EPT];
  int bk[EPT];
  if (e0 + CHUNK <= N_EDGES) {          // fast path (2604 of 2605 blocks)
    int cv[EPT], rv[EPT];
    float wf[EPT];
#pragma unroll
    for (int k = 0; k < EPT; ++k) {
      int e = e0 + k * FBLK + t;
      cv[k] = col[e];
      rv[k] = row[e];
      wf[k] = ew[e];
    }
    __builtin_amdgcn_sched_barrier(0);  // 36 loads in flight before any use
#pragma unroll
    for (int k = 0; k < EPT; ++k) {
      pk[k] = ((unsigned)rv[k] << BSHIFT) | (unsigned)(cv[k] & (BNODES - 1));
      wv[k] = f2bf(wf[k]);
      bk[k] = cv[k] >> BSHIFT;
    }
#pragma unroll
    for (int k = 0; k < EPT; ++k) atomicAdd(&lhist[bk[k]], 1u);
  } else {
#pragma unroll
    for (int k = 0; k < EPT; ++k) {
      int e = e0 + k * FBLK + t;
      bk[k] = -1;
      if (e < N_EDGES) {
        int c = col[e];
        pk[k] = ((unsigned)row[e] << BSHIFT) | (unsigned)(c & (BNODES - 1));
        wv[k] = f2bf(ew[e]);
        bk[k] = c >> BSHIFT;
        atomicAdd(&lhist[bk[k]], 1u);
      }
    }
  }
  __syncthreads();                                        // B2

  // exclusive prefix over FBLK bucket counts: wave scan + 8-entry fixup
  unsigned own = lhist[t];
  unsigned v = own;
#pragma unroll
  for (int d = 1; d < 64; d <<= 1) {
    unsigned u = __shfl_up(v, d, 64);
    if ((t & 63) >= d) v += u;
  }
  if ((t & 63) == 63) wsum[t >> 6] = v;
  __syncthreads();                                        // B3
  unsigned wbase = 0;
  unsigned total = 0;
#pragma unroll
  for (int w = 0; w < FBLK / 64; ++w) {
    if (w < (t >> 6)) wbase += wsum[w];
    total += wsum[w];
  }
  unsigned ex = wbase + v - own;
  lb[t] = ex;
  tail[t] = ex;
  __syncthreads();                                        // B4

  if (e0 + CHUNK <= N_EDGES) {
#pragma unroll
    for (int k = 0; k < EPT; ++k) {
      unsigned s = atomicAdd(&tail[bk[k]], 1u);
      spk[s] = pk[k];
      sw[s] = wv[k];
      sbkt[s] = (unsigned short)bk[k];
    }
  } else {
#pragma unroll
    for (int k = 0; k < EPT; ++k) {
      if (bk[k] >= 0) {
        unsigned s = atomicAdd(&tail[bk[k]], 1u);
        spk[s] = pk[k];
        sw[s] = wv[k];
        sbkt[s] = (unsigned short)bk[k];
      }
    }
  }
  __syncthreads();                                        // B5

  // staged order is bucket-sorted: consecutive s -> consecutive global dest.
  unsigned s = t;
  for (; s + 3u * FBLK < total; s += 4u * FBLK) {
#pragma unroll
    for (int u = 0; u < 4; ++u) {
      unsigned si = s + u * FBLK;
      unsigned b = sbkt[si];
      unsigned idx = gbase[b] + (si - lb[b]);
      PK[idx] = spk[si];
      W16[idx] = sw[si];
    }
  }
  for (; s < total; s += FBLK) {
    unsigned b = sbkt[s];
    unsigned idx = gbase[b] + (s - lb[b]);
    PK[idx] = spk[s];
    W16[idx] = sw[s];
  }
}

// ---------------- accumulate: one (bucket,part) per block ----------------
// mode 0: val = ew (weighted degree). mode 1: val = ew * bf16 p16[row].
// SoA reads: per 8 records = 2x uint4 (PK) + 1x uint4 (8 bf16 W16) = 3 loads.
// 16 records in flight per thread; sched_barrier pins the batches.
constexpr int ABLK = 512;
__global__ __launch_bounds__(ABLK) void k_acc(const unsigned* __restrict__ PK,
                                              const unsigned short* __restrict__ W16,
                                              const unsigned* __restrict__ hist,
                                              const unsigned short* __restrict__ p16,
                                              float* __restrict__ out,
                                              int mode, int split) {
  __shared__ float acc[BNODES];
  {
    float4* a4 = (float4*)acc;
#pragma unroll
    for (int i = threadIdx.x; i < BNODES / 4; i += ABLK)
      a4[i] = make_float4(0.f, 0.f, 0.f, 0.f);
  }
  __syncthreads();
  int b = blockIdx.x / split;
  int part = blockIdx.x - b * split;
  unsigned bs = hist[(size_t)b * NBLK];
  unsigned be = (b + 1 < NB) ? hist[(size_t)(b + 1) * NBLK] : (unsigned)N_EDGES;
  unsigned len = be - bs;
  unsigned s = bs + (unsigned)(((unsigned long long)len * part) / split);
  unsigned e = bs + (unsigned)(((unsigned long long)len * (part + 1)) / split);
  unsigned t = threadIdx.x;

  unsigned s_al = (s + 7u) & ~7u;        // align to 8 records for uint4 W16
  if (s_al > e) s_al = e;
  if (t == 0) {                          // scalar head (<8 records)
    for (unsigned i = s; i < s_al; ++i) {
      unsigned pk = PK[i];
      float v = bf2f(W16[i]);
      if (mode) v *= bf2f(p16[pk >> BSHIFT]);
      atomicAdd(&acc[pk & (BNODES - 1)], v);
    }
  }
  s = s_al;
  unsigned n = (e > s) ? (e - s) : 0u;
  unsigned ng = n >> 3;                  // groups of 8 records
  const uint4* pk4 = (const uint4*)(PK + s);    // group g: pk4[2g], pk4[2g+1]
  const uint4* w4  = (const uint4*)(W16 + s);   // group g: w4[g] (8 bf16)

  unsigned ip = t;
  for (; ip + ABLK < ng; ip += 2u * ABLK) {     // 2 groups = 16 records
    unsigned g1 = ip + ABLK;
    uint4 pA0 = pk4[2u * ip], pA1 = pk4[2u * ip + 1u];
    uint4 pB0 = pk4[2u * g1], pB1 = pk4[2u * g1 + 1u];
    uint4 wA = w4[ip], wB = w4[g1];
    __builtin_amdgcn_sched_barrier(0);   // 6 loads issued before any use
    unsigned pks[16] = {pA0.x, pA0.y, pA0.z, pA0.w, pA1.x, pA1.y, pA1.z, pA1.w,
                        pB0.x, pB0.y, pB0.z, pB0.w, pB1.x, pB1.y, pB1.z, pB1.w};
    unsigned ws[8] = {wA.x, wA.y, wA.z, wA.w, wB.x, wB.y, wB.z, wB.w};
    float v[16];
#pragma unroll
    for (int j = 0; j < 16; ++j)
      v[j] = bf2f((unsigned short)((j & 1) ? (ws[j >> 1] >> 16)
                                           : (ws[j >> 1] & 0xFFFFu)));
    if (mode) {
      unsigned short g[16];
#pragma unroll
      for (int j = 0; j < 16; ++j) g[j] = p16[pks[j] >> BSHIFT];
      __builtin_amdgcn_sched_barrier(0); // 16 gathers in flight before use
#pragma unroll
      for (int j = 0; j < 16; ++j) v[j] *= bf2f(g[j]);
    }
#pragma unroll
    for (int j = 0; j < 16; ++j)
      atomicAdd(&acc[pks[j] & (BNODES - 1)], v[j]);
  }
  for (; ip < ng; ip += 2u * ABLK) {     // leftover single group (8 records)
    uint4 p0 = pk4[2u * ip], p1 = pk4[2u * ip + 1u];
    uint4 w = w4[ip];
    unsigned pks[8] = {p0.x, p0.y, p0.z, p0.w, p1.x, p1.y, p1.z, p1.w};
    unsigned ws[4] = {w.x, w.y, w.z, w.w};
#pragma unroll
    for (int j = 0; j < 8; ++j) {
      float v = bf2f((unsigned short)((j & 1) ? (ws[j >> 1] >> 16)
                                              : (ws[j >> 1] & 0xFFFFu)));
      if (mode) v *= bf2f(p16[pks[j] >> BSHIFT]);
      atomicAdd(&acc[pks[j] & (BNODES - 1)], v);
    }
  }
  unsigned rem = n & 7u;                 // scalar tail, threads 0..rem-1
  if (t < rem) {
    unsigned i = s + (n - rem) + t;
    unsigned pk = PK[i];
    float v = bf2f(W16[i]);
    if (mode) v *= bf2f(p16[pk >> BSHIFT]);
    atomicAdd(&acc[pk & (BNODES - 1)], v);
  }
  __syncthreads();

  float* o = out + (size_t)part * N_NODES;
  int base = b * BNODES;
  if (base + BNODES <= N_NODES) {        // full bucket: float4 writeout
    float4* o4 = (float4*)(o + base);
    const float4* a4 = (const float4*)acc;
#pragma unroll
    for (int j = threadIdx.x; j < BNODES / 4; j += ABLK) o4[j] = a4[j];
  } else {
    for (int j = threadIdx.x; base + j < N_NODES; j += ABLK) o[base + j] = acc[j];
  }
}

// ---------------- node-wise kernels ----------------

__global__ void k_dis_p(const float* __restrict__ x, const float* __restrict__ D,
                        float* __restrict__ A, unsigned short* __restrict__ P16,
                        int split) {
  int i = blockIdx.x * blockDim.x + threadIdx.x;
  if (i >= N_NODES) return;
  float deg = 1.0f;                       // self loop
  for (int j = 0; j < split; ++j) deg += D[(size_t)j * N_NODES + i];
  float d = rsqrtf(deg);
  A[i] = d;
  P16[i] = f2bf(d * x[i]);
}

__global__ void k_g2(const float* __restrict__ A, const float* __restrict__ x,
                     const float* __restrict__ D, unsigned short* __restrict__ P16,
                     const float* __restrict__ W1, const float* __restrict__ b1,
                     const float* __restrict__ W2, int split) {
  int i = blockIdx.x * blockDim.x + threadIdx.x;
  if (i >= N_NODES) return;
  float d = A[i];
  float sraw = 0.f;
  for (int j = 0; j < split; ++j) sraw += D[(size_t)j * N_NODES + i];
  float s1 = d * sraw + d * d * x[i];
  float g = 0.f;
#pragma unroll
  for (int j = 0; j < 4; ++j) {
    float h = fmaf(s1, W1[j], b1[j]);
    g = fmaf(fmaxf(h, 0.f), W2[j], g);
  }
  P16[i] = f2bf(d * g);
}

__global__ void k_out2(const float* __restrict__ A,
                       const unsigned short* __restrict__ P16,
                       const float* __restrict__ D, const float* __restrict__ b2,
                       const float* __restrict__ Wl, const float* __restrict__ bl,
                       float* __restrict__ y, int split) {
  int i = blockIdx.x * blockDim.x + threadIdx.x;
  if (i >= N_NODES) return;
  float d = A[i];
  float g = bf2f(P16[i]) / d;             // d in (0,1], safe
  float sraw = 0.f;
  for (int j = 0; j < split; ++j) sraw += D[(size_t)j * N_NODES + i];
  float agg2 = d * sraw + d * d * g;
  float v = fmaf(agg2 + b2[0], Wl[0], bl[0]);
  y[i] = 1.0f / (1.0f + expf(-v));
}

// ---------------- fallback (round-2 global-atomic path) ----------------

__global__ void f_deg(const int* __restrict__ col, const float* __restrict__ ew,
                      float* __restrict__ deg) {
  int i = blockIdx.x * blockDim.x + threadIdx.x;
  int stride = gridDim.x * blockDim.x;
  for (int e = i; e < N_EDGES; e += stride) atomicAdd(&deg[col[e]], ew[e]);
}
__global__ void f_dis(float* __restrict__ a) {
  int i = blockIdx.x * blockDim.x + threadIdx.x;
  if (i < N_NODES) a[i] = rsqrtf(a[i] + 1.0f);
}
__global__ void f_scatter(const int* __restrict__ row, const int* __restrict__ col,
                          const float* __restrict__ ew, const float* __restrict__ dis,
                          const float* __restrict__ src, float* __restrict__ acc) {
  int i = blockIdx.x * blockDim.x + threadIdx.x;
  int stride = gridDim.x * blockDim.x;
  for (int e = i; e < N_EDGES; e += stride) {
    int r = row[e]; int c = col[e];
    atomicAdd(&acc[c], dis[r] * ew[e] * src[r]);
  }
}
__global__ void f_g(const float* __restrict__ dis, const float* __restrict__ x,
                    float* __restrict__ s1g, const float* __restrict__ W1,
                    const float* __restrict__ b1, const float* __restrict__ W2) {
  int i = blockIdx.x * blockDim.x + threadIdx.x;
  if (i >= N_NODES) return;
  float d = dis[i];
  float s1 = d * s1g[i] + d * d * x[i];
  float g = 0.f;
#pragma unroll
  for (int j = 0; j < 4; ++j) {
    float h = fmaf(s1, W1[j], b1[j]);
    g = fmaf(fmaxf(h, 0.f), W2[j], g);
  }
  s1g[i] = g;
}
__global__ void f_out(const float* __restrict__ dis, const float* __restrict__ g,
                      float* __restrict__ s2out, const float* __restrict__ b2,
                      const float* __restrict__ Wl, const float* __restrict__ bl) {
  int i = blockIdx.x * blockDim.x + threadIdx.x;
  if (i >= N_NODES) return;
  float d = dis[i];
  float agg2 = d * s2out[i] + d * d * g[i];
  float v = fmaf(agg2 + b2[0], Wl[0], bl[0]);
  s2out[i] = 1.0f / (1.0f + expf(-v));
}

// ---------------- launch ----------------

extern "C" void kernel_launch(void* const* d_in, const int* in_sizes, int n_in,
                              void* d_out, int out_size, void* d_ws, size_t ws_size,
                              hipStream_t stream) {
  const float* x  = (const float*)d_in[0];
  const int* ei   = (const int*)d_in[1];   // int32 (harness narrows int64)
  const float* ew = (const float*)d_in[2];
  const float* W1 = (const float*)d_in[3];
  const float* b1 = (const float*)d_in[4];
  const float* W2 = (const float*)d_in[5];
  const float* b2 = (const float*)d_in[6];
  const float* Wl = (const float*)d_in[7];
  const float* bl = (const float*)d_in[8];

  const int* row = ei;
  const int* col = ei + N_EDGES;

  auto pad = [](size_t v) { return (v + 255) & ~(size_t)255; };
  const size_t PK_B    = pad((size_t)N_EDGES * 4);         // 64,000,000
  const size_t W16_B   = pad((size_t)N_EDGES * 2);         // 32,000,000
  const size_t HIST_B  = pad((size_t)NHIST_PAD * 4);       // 2,555,904
  const size_t HISTT_B = pad((size_t)NBLK * 256 * 4);      // 2,667,520
  const size_t BSUM_B  = 8192;
  const size_t NODE_B  = pad((size_t)N_NODES * 4);
  const size_t P16_B   = pad((size_t)N_NODES * 2);
  const size_t BASE    = PK_B + W16_B + HIST_B + HISTT_B + BSUM_B + NODE_B + P16_B;

  dim3 blk(256);
  dim3 ngrid((N_NODES + 255) / 256);
  dim3 tgrid((NBLK + 31) / 32, 8);
  dim3 tblk(32, 32);

  int split = 0;
  for (int s : {4, 2, 1})
    if (ws_size >= BASE + (size_t)s * NODE_B) { split = s; break; }

  if (split) {
    char* w = (char*)d_ws;
    unsigned* PK        = (unsigned*)w;
    unsigned short* W16 = (unsigned short*)(w + PK_B);
    unsigned* hist      = (unsigned*)(w + PK_B + W16_B);
    unsigned* histT     = (unsigned*)(w + PK_B + W16_B + HIST_B);  // also histT2
    unsigned* bsum      = (unsigned*)(w + PK_B + W16_B + HIST_B + HISTT_B);
    float* A            = (float*)(w + PK_B + W16_B + HIST_B + HISTT_B + BSUM_B);
    unsigned short* P16 = (unsigned short*)((char*)A + NODE_B);
    float* D            = (float*)((char*)P16 + P16_B);    // split partials

    // zero the scan pad tail (rest of hist fully written by k_t1)
    hipMemsetAsync(hist + NHIST, 0, (size_t)(NHIST_PAD - NHIST) * 4, stream);

    k_count<<<NBLK, FBLK, 0, stream>>>(col, histT);
    k_t1   <<<tgrid, tblk, 0, stream>>>(histT, hist);
    k_scanA<<<NSCAN, SCAN_TPB, 0, stream>>>(hist, bsum);
    k_scanB<<<1, 1024, 0, stream>>>(bsum);
    k_scanC<<<NSCAN, SCAN_TPB, 0, stream>>>(hist, bsum);
    k_t2   <<<tgrid, tblk, 0, stream>>>(hist, histT);      // offsets, transposed
    k_fill <<<NBLK, FBLK, 0, stream>>>(row, col, ew, histT, PK, W16);

    k_acc  <<<NB * split, ABLK, 0, stream>>>(PK, W16, hist, nullptr, D, 0, split);
    k_dis_p<<<ngrid, blk, 0, stream>>>(x, D, A, P16, split);
    k_acc  <<<NB * split, ABLK, 0, stream>>>(PK, W16, hist, P16, D, 1, split);
    k_g2   <<<ngrid, blk, 0, stream>>>(A, x, D, P16, W1, b1, W2, split);
    k_acc  <<<NB * split, ABLK, 0, stream>>>(PK, W16, hist, P16, D, 1, split);
    k_out2 <<<ngrid, blk, 0, stream>>>(A, P16, D, b2, Wl, bl, (float*)d_out, split);
  } else {
    float* Aw = (float*)d_ws;
    float* Bw = Aw + N_NODES;
    float* Cw = (float*)d_out;
    hipMemsetAsync(d_ws, 0, 2ull * N_NODES * 4, stream);
    hipMemsetAsync(d_out, 0, (size_t)N_NODES * 4, stream);
    dim3 egrid(4096);
    f_deg<<<egrid, blk, 0, stream>>>(col, ew, Aw);
    f_dis<<<ngrid, blk, 0, stream>>>(Aw);
    f_scatter<<<egrid, blk, 0, stream>>>(row, col, ew, Aw, x, Bw);
    f_g<<<ngrid, blk, 0, stream>>>(Aw, x, Bw, W1, b1, W2);
    f_scatter<<<egrid, blk, 0, stream>>>(row, col, ew, Aw, Bw, Cw);
    f_out<<<ngrid, blk, 0, stream>>>(Aw, Bw, Cw, b2, Wl, bl);
  }
}

// Round 14
// 412.540 us; speedup vs baseline: 1.0331x; 1.0331x over previous
//
#include <hip/hip_runtime.h>

// GCN on 1M nodes / 16M edges, collapsed to scalar per-node features.
//
//   deg[c]  = sum_{e: col=c} ew[e] + 1 (self loop)
//   dis     = rsqrt(deg)
//   S1[c]   = dis[c] * (sum_e dis[row]*ew*x[row]) + dis[c]^2 * x[c]
//   g[c]    = sum_j relu(S1[c]*W1[j] + b1[j]) * W2[j]
//   S2[c]   = dis[c] * (sum_e dis[row]*ew*g[row]) + dis[c]^2 * g[c]
//   y[c]    = sigmoid((S2[c]+b2)*Wl + bl)
//
// R13 post-mortem: SoA fill = big win (fill 108 -> ~50us, gone from top-5),
// but acc regressed 104 -> 116 despite fewer bytes/loads. Suspects: 16-wide
// aggregate-init local arrays (promotion failure -> extra moves) and 2-op-
// per-value bf16 unpack in the atomic loop. R14: same load rhythm, explicit
// named uint4 fields (zero local arrays), 1-op bf16 unpack (hi = u & mask,
// lo = u << 16).

constexpr int N_NODES = 1000000;
constexpr int N_EDGES = 16000000;

constexpr int BSHIFT = 12;
constexpr int BNODES = 1 << BSHIFT;                    // 4096 nodes/bucket
constexpr int NB = (N_NODES + BNODES - 1) / BNODES;    // 245 buckets
constexpr int EPT = 12;                                // edges/thread in count+fill
constexpr int FBLK = 512;                              // threads in count+fill
constexpr int CHUNK = FBLK * EPT;                      // 6144 edges/block
constexpr int NBLK = (N_EDGES + CHUNK - 1) / CHUNK;    // 2605
constexpr int NHIST = NB * NBLK;                       // 638,225
constexpr int SCAN_TPB = 256;
constexpr int SCAN_EPB = 1024;
constexpr int NSCAN = (NHIST + SCAN_EPB - 1) / SCAN_EPB;  // 624
constexpr int NHIST_PAD = NSCAN * SCAN_EPB;            // 638,976

__device__ inline unsigned short f2bf(float f) {   // fp32 -> bf16 RNE
  unsigned u = __float_as_uint(f);
  return (unsigned short)((u + 0x7FFFu + ((u >> 16) & 1u)) >> 16);
}
__device__ inline float bf2f(unsigned short h) {
  return __uint_as_float((unsigned)h << 16);
}
// packed-pair bf16 unpack: lo = u<<16 (1 op), hi = u & 0xFFFF0000 (1 op)
__device__ inline float blo(unsigned u) { return __uint_as_float(u << 16); }
__device__ inline float bhi(unsigned u) { return __uint_as_float(u & 0xFFFF0000u); }

// ---------------- build: count / transpose / scan / transpose / fill --------

// histT layout [NBLK][256]: block writes its own contiguous row (coalesced).
__global__ __launch_bounds__(FBLK) void k_count(const int* __restrict__ col,
                                                unsigned* __restrict__ histT) {
  __shared__ unsigned cnt[256];
  int t = threadIdx.x;
  if (t < 256) cnt[t] = 0;
  __syncthreads();
  int e0 = blockIdx.x * CHUNK;
  if (e0 + CHUNK <= N_EDGES) {          // fast path: all loads unguarded
    int c[EPT];
#pragma unroll
    for (int k = 0; k < EPT; ++k) c[k] = col[e0 + k * FBLK + t];
    __builtin_amdgcn_sched_barrier(0);  // keep the load batch issued together
#pragma unroll
    for (int k = 0; k < EPT; ++k) atomicAdd(&cnt[c[k] >> BSHIFT], 1u);
  } else {
#pragma unroll
    for (int k = 0; k < EPT; ++k) {
      int e = e0 + k * FBLK + t;
      if (e < N_EDGES) atomicAdd(&cnt[col[e] >> BSHIFT], 1u);
    }
  }
  __syncthreads();
  if (t < 256) histT[(size_t)blockIdx.x * 256 + t] = cnt[t];
}

// histT[NBLK][256] -> hist[b*NBLK + blk] (bucket-major flat, for linear scan)
__global__ __launch_bounds__(1024) void k_t1(const unsigned* __restrict__ in,
                                             unsigned* __restrict__ out) {
  __shared__ unsigned tile[32][33];
  int bx = blockIdx.x * 32;   // blk base
  int by = blockIdx.y * 32;   // b base
  int tx = threadIdx.x, ty = threadIdx.y;
  int rblk = bx + ty;
  if (rblk < NBLK) tile[ty][tx] = in[(size_t)rblk * 256 + by + tx];
  __syncthreads();
  int wb = by + ty, wblk = bx + tx;
  if (wb < NB && wblk < NBLK) out[(size_t)wb * NBLK + wblk] = tile[tx][ty];
}

// hist offsets (bucket-major) -> histT2[blk*256 + b] (fill reads coalesced)
__global__ __launch_bounds__(1024) void k_t2(const unsigned* __restrict__ in,
                                             unsigned* __restrict__ out) {
  __shared__ unsigned tile[32][33];
  int bx = blockIdx.x * 32;   // blk base
  int by = blockIdx.y * 32;   // b base
  int tx = threadIdx.x, ty = threadIdx.y;
  int rb = by + ty, rblk = bx + tx;
  if (rb < NB && rblk < NBLK) tile[ty][tx] = in[(size_t)rb * NBLK + rblk];
  __syncthreads();
  int wblk = bx + ty, wb = by + tx;
  if (wblk < NBLK && wb < NB) out[(size_t)wblk * 256 + wb] = tile[tx][ty];
}

__global__ __launch_bounds__(SCAN_TPB) void k_scanA(unsigned* __restrict__ h,
                                                    unsigned* __restrict__ bsum) {
  __shared__ unsigned sc[SCAN_TPB];
  int t = threadIdx.x;
  size_t base = (size_t)blockIdx.x * SCAN_EPB + (size_t)t * 4;
  uint4 v = *(const uint4*)(h + base);
  unsigned s = v.x + v.y + v.z + v.w;
  sc[t] = s;
  __syncthreads();
  for (int d = 1; d < SCAN_TPB; d <<= 1) {
    unsigned u = (t >= d) ? sc[t - d] : 0;
    __syncthreads();
    sc[t] += u;
    __syncthreads();
  }
  unsigned ex = sc[t] - s;
  uint4 o;
  o.x = ex; o.y = ex + v.x; o.z = ex + v.x + v.y; o.w = ex + v.x + v.y + v.z;
  *(uint4*)(h + base) = o;
  if (t == SCAN_TPB - 1) bsum[blockIdx.x] = sc[t];
}

__global__ __launch_bounds__(1024) void k_scanB(unsigned* __restrict__ bsum) {
  __shared__ unsigned sc[1024];
  int t = threadIdx.x;
  unsigned a0 = (2 * t < NSCAN) ? bsum[2 * t] : 0;
  unsigned a1 = (2 * t + 1 < NSCAN) ? bsum[2 * t + 1] : 0;
  unsigned s = a0 + a1;
  sc[t] = s;
  __syncthreads();
  for (int d = 1; d < 1024; d <<= 1) {
    unsigned u = (t >= d) ? sc[t - d] : 0;
    __syncthreads();
    sc[t] += u;
    __syncthreads();
  }
  unsigned ex = sc[t] - s;
  if (2 * t < NSCAN) bsum[2 * t] = ex;
  if (2 * t + 1 < NSCAN) bsum[2 * t + 1] = ex + a0;
}

__global__ __launch_bounds__(SCAN_TPB) void k_scanC(unsigned* __restrict__ h,
                                                    const unsigned* __restrict__ bsum) {
  unsigned add = bsum[blockIdx.x];
  size_t base = (size_t)blockIdx.x * SCAN_EPB + (size_t)threadIdx.x * 4;
  uint4 v = *(uint4*)(h + base);
  v.x += add; v.y += add; v.z += add; v.w += add;
  *(uint4*)(h + base) = v;
}

// Register-stash + LDS-reorder fill, SoA output: PK (u32) + W16 (bf16).
// pk = row<<12 | col&0xFFF; row < 2^20 fits.
__global__ __launch_bounds__(FBLK) void k_fill(const int* __restrict__ row,
                                               const int* __restrict__ col,
                                               const float* __restrict__ ew,
                                               const unsigned* __restrict__ histT2,
                                               unsigned* __restrict__ PK,
                                               unsigned short* __restrict__ W16) {
  __shared__ unsigned lhist[FBLK];
  __shared__ unsigned lb[FBLK];
  __shared__ unsigned tail[FBLK];
  __shared__ unsigned gbase[NB];
  __shared__ unsigned wsum[FBLK / 64];
  __shared__ unsigned spk[CHUNK];          // 24KB
  __shared__ unsigned short sw[CHUNK];     // 12KB
  __shared__ unsigned short sbkt[CHUNK];   // 12KB

  int t = threadIdx.x;
  int blk = blockIdx.x;
  lhist[t] = 0;
  if (t < NB) gbase[t] = histT2[(size_t)blk * 256 + t];  // coalesced row read
  __syncthreads();                                        // B1

  int e0 = blk * CHUNK;
  unsigned pk[EPT];
  unsigned short wv[EPT];
  int bk[EPT];
  if (e0 + CHUNK <= N_EDGES) {          // fast path (2604 of 2605 blocks)
    int cv[EPT], rv[EPT];
    float wf[EPT];
#pragma unroll
    for (int k = 0; k < EPT; ++k) {
      int e = e0 + k * FBLK + t;
      cv[k] = col[e];
      rv[k] = row[e];
      wf[k] = ew[e];
    }
    __builtin_amdgcn_sched_barrier(0);  // 36 loads in flight before any use
#pragma unroll
    for (int k = 0; k < EPT; ++k) {
      pk[k] = ((unsigned)rv[k] << BSHIFT) | (unsigned)(cv[k] & (BNODES - 1));
      wv[k] = f2bf(wf[k]);
      bk[k] = cv[k] >> BSHIFT;
    }
#pragma unroll
    for (int k = 0; k < EPT; ++k) atomicAdd(&lhist[bk[k]], 1u);
  } else {
#pragma unroll
    for (int k = 0; k < EPT; ++k) {
      int e = e0 + k * FBLK + t;
      bk[k] = -1;
      if (e < N_EDGES) {
        int c = col[e];
        pk[k] = ((unsigned)row[e] << BSHIFT) | (unsigned)(c & (BNODES - 1));
        wv[k] = f2bf(ew[e]);
        bk[k] = c >> BSHIFT;
        atomicAdd(&lhist[bk[k]], 1u);
      }
    }
  }
  __syncthreads();                                        // B2

  // exclusive prefix over FBLK bucket counts: wave scan + 8-entry fixup
  unsigned own = lhist[t];
  unsigned v = own;
#pragma unroll
  for (int d = 1; d < 64; d <<= 1) {
    unsigned u = __shfl_up(v, d, 64);
    if ((t & 63) >= d) v += u;
  }
  if ((t & 63) == 63) wsum[t >> 6] = v;
  __syncthreads();                                        // B3
  unsigned wbase = 0;
  unsigned total = 0;
#pragma unroll
  for (int w = 0; w < FBLK / 64; ++w) {
    if (w < (t >> 6)) wbase += wsum[w];
    total += wsum[w];
  }
  unsigned ex = wbase + v - own;
  lb[t] = ex;
  tail[t] = ex;
  __syncthreads();                                        // B4

  if (e0 + CHUNK <= N_EDGES) {
#pragma unroll
    for (int k = 0; k < EPT; ++k) {
      unsigned s = atomicAdd(&tail[bk[k]], 1u);
      spk[s] = pk[k];
      sw[s] = wv[k];
      sbkt[s] = (unsigned short)bk[k];
    }
  } else {
#pragma unroll
    for (int k = 0; k < EPT; ++k) {
      if (bk[k] >= 0) {
        unsigned s = atomicAdd(&tail[bk[k]], 1u);
        spk[s] = pk[k];
        sw[s] = wv[k];
        sbkt[s] = (unsigned short)bk[k];
      }
    }
  }
  __syncthreads();                                        // B5

  // staged order is bucket-sorted: consecutive s -> consecutive global dest.
  unsigned s = t;
  for (; s + 3u * FBLK < total; s += 4u * FBLK) {
#pragma unroll
    for (int u = 0; u < 4; ++u) {
      unsigned si = s + u * FBLK;
      unsigned b = sbkt[si];
      unsigned idx = gbase[b] + (si - lb[b]);
      PK[idx] = spk[si];
      W16[idx] = sw[si];
    }
  }
  for (; s < total; s += FBLK) {
    unsigned b = sbkt[s];
    unsigned idx = gbase[b] + (s - lb[b]);
    PK[idx] = spk[s];
    W16[idx] = sw[s];
  }
}

// ---------------- accumulate: one (bucket,part) per block ----------------
// mode 0: val = ew. mode 1: val = ew * bf16 p16[row].
// Per 16 records: 4x uint4 PK + 2x uint4 W16 = 6 loads, all named fields,
// zero local arrays. blo/bhi = 1-VALU-op bf16 unpack.
constexpr int ABLK = 512;

#define GPAIR(P, GA, GB) \
  unsigned short GA = p16[(P).x >> BSHIFT], GB = p16[(P).y >> BSHIFT]; \
  unsigned short GA##z = p16[(P).z >> BSHIFT], GB##w = p16[(P).w >> BSHIFT];

__global__ __launch_bounds__(ABLK) void k_acc(const unsigned* __restrict__ PK,
                                              const unsigned short* __restrict__ W16,
                                              const unsigned* __restrict__ hist,
                                              const unsigned short* __restrict__ p16,
                                              float* __restrict__ out,
                                              int mode, int split) {
  __shared__ float acc[BNODES];
  {
    float4* a4 = (float4*)acc;
#pragma unroll
    for (int i = threadIdx.x; i < BNODES / 4; i += ABLK)
      a4[i] = make_float4(0.f, 0.f, 0.f, 0.f);
  }
  __syncthreads();
  int b = blockIdx.x / split;
  int part = blockIdx.x - b * split;
  unsigned bs = hist[(size_t)b * NBLK];
  unsigned be = (b + 1 < NB) ? hist[(size_t)(b + 1) * NBLK] : (unsigned)N_EDGES;
  unsigned len = be - bs;
  unsigned s = bs + (unsigned)(((unsigned long long)len * part) / split);
  unsigned e = bs + (unsigned)(((unsigned long long)len * (part + 1)) / split);
  unsigned t = threadIdx.x;

  unsigned s_al = (s + 7u) & ~7u;        // align to 8 records
  if (s_al > e) s_al = e;
  if (t == 0) {                          // scalar head (<8 records)
    for (unsigned i = s; i < s_al; ++i) {
      unsigned pk = PK[i];
      float v = bf2f(W16[i]);
      if (mode) v *= bf2f(p16[pk >> BSHIFT]);
      atomicAdd(&acc[pk & (BNODES - 1)], v);
    }
  }
  s = s_al;
  unsigned n = (e > s) ? (e - s) : 0u;
  unsigned ng = n >> 3;                  // groups of 8 records
  const uint4* pk4 = (const uint4*)(PK + s);    // group g: pk4[2g], pk4[2g+1]
  const uint4* w4  = (const uint4*)(W16 + s);   // group g: w4[g] (8 bf16)

  unsigned ip = t;
  for (; ip + ABLK < ng; ip += 2u * ABLK) {     // 2 groups = 16 records
    unsigned g1 = ip + ABLK;
    uint4 pA0 = pk4[2u * ip], pA1 = pk4[2u * ip + 1u];
    uint4 pB0 = pk4[2u * g1], pB1 = pk4[2u * g1 + 1u];
    uint4 wA = w4[ip], wB = w4[g1];
    __builtin_amdgcn_sched_barrier(0);   // 6 loads issued before any use
    if (mode) {
      unsigned short gA0 = p16[pA0.x >> BSHIFT], gA1 = p16[pA0.y >> BSHIFT];
      unsigned short gA2 = p16[pA0.z >> BSHIFT], gA3 = p16[pA0.w >> BSHIFT];
      unsigned short gA4 = p16[pA1.x >> BSHIFT], gA5 = p16[pA1.y >> BSHIFT];
      unsigned short gA6 = p16[pA1.z >> BSHIFT], gA7 = p16[pA1.w >> BSHIFT];
      unsigned short gB0 = p16[pB0.x >> BSHIFT], gB1 = p16[pB0.y >> BSHIFT];
      unsigned short gB2 = p16[pB0.z >> BSHIFT], gB3 = p16[pB0.w >> BSHIFT];
      unsigned short gB4 = p16[pB1.x >> BSHIFT], gB5 = p16[pB1.y >> BSHIFT];
      unsigned short gB6 = p16[pB1.z >> BSHIFT], gB7 = p16[pB1.w >> BSHIFT];
      __builtin_amdgcn_sched_barrier(0); // 16 gathers in flight before use
      atomicAdd(&acc[pA0.x & (BNODES - 1)], blo(wA.x) * bf2f(gA0));
      atomicAdd(&acc[pA0.y & (BNODES - 1)], bhi(wA.x) * bf2f(gA1));
      atomicAdd(&acc[pA0.z & (BNODES - 1)], blo(wA.y) * bf2f(gA2));
      atomicAdd(&acc[pA0.w & (BNODES - 1)], bhi(wA.y) * bf2f(gA3));
      atomicAdd(&acc[pA1.x & (BNODES - 1)], blo(wA.z) * bf2f(gA4));
      atomicAdd(&acc[pA1.y & (BNODES - 1)], bhi(wA.z) * bf2f(gA5));
      atomicAdd(&acc[pA1.z & (BNODES - 1)], blo(wA.w) * bf2f(gA6));
      atomicAdd(&acc[pA1.w & (BNODES - 1)], bhi(wA.w) * bf2f(gA7));
      atomicAdd(&acc[pB0.x & (BNODES - 1)], blo(wB.x) * bf2f(gB0));
      atomicAdd(&acc[pB0.y & (BNODES - 1)], bhi(wB.x) * bf2f(gB1));
      atomicAdd(&acc[pB0.z & (BNODES - 1)], blo(wB.y) * bf2f(gB2));
      atomicAdd(&acc[pB0.w & (BNODES - 1)], bhi(wB.y) * bf2f(gB3));
      atomicAdd(&acc[pB1.x & (BNODES - 1)], blo(wB.z) * bf2f(gB4));
      atomicAdd(&acc[pB1.y & (BNODES - 1)], bhi(wB.z) * bf2f(gB5));
      atomicAdd(&acc[pB1.z & (BNODES - 1)], blo(wB.w) * bf2f(gB6));
      atomicAdd(&acc[pB1.w & (BNODES - 1)], bhi(wB.w) * bf2f(gB7));
    } else {
      atomicAdd(&acc[pA0.x & (BNODES - 1)], blo(wA.x));
      atomicAdd(&acc[pA0.y & (BNODES - 1)], bhi(wA.x));
      atomicAdd(&acc[pA0.z & (BNODES - 1)], blo(wA.y));
      atomicAdd(&acc[pA0.w & (BNODES - 1)], bhi(wA.y));
      atomicAdd(&acc[pA1.x & (BNODES - 1)], blo(wA.z));
      atomicAdd(&acc[pA1.y & (BNODES - 1)], bhi(wA.z));
      atomicAdd(&acc[pA1.z & (BNODES - 1)], blo(wA.w));
      atomicAdd(&acc[pA1.w & (BNODES - 1)], bhi(wA.w));
      atomicAdd(&acc[pB0.x & (BNODES - 1)], blo(wB.x));
      atomicAdd(&acc[pB0.y & (BNODES - 1)], bhi(wB.x));
      atomicAdd(&acc[pB0.z & (BNODES - 1)], blo(wB.y));
      atomicAdd(&acc[pB0.w & (BNODES - 1)], bhi(wB.y));
      atomicAdd(&acc[pB1.x & (BNODES - 1)], blo(wB.z));
      atomicAdd(&acc[pB1.y & (BNODES - 1)], bhi(wB.z));
      atomicAdd(&acc[pB1.z & (BNODES - 1)], blo(wB.w));
      atomicAdd(&acc[pB1.w & (BNODES - 1)], bhi(wB.w));
    }
  }
  for (; ip < ng; ip += 2u * ABLK) {     // leftover single group (8 records)
    uint4 p0 = pk4[2u * ip], p1 = pk4[2u * ip + 1u];
    uint4 w = w4[ip];
    float v0 = blo(w.x), v1 = bhi(w.x), v2 = blo(w.y), v3 = bhi(w.y);
    float v4 = blo(w.z), v5 = bhi(w.z), v6 = blo(w.w), v7 = bhi(w.w);
    if (mode) {
      v0 *= bf2f(p16[p0.x >> BSHIFT]); v1 *= bf2f(p16[p0.y >> BSHIFT]);
      v2 *= bf2f(p16[p0.z >> BSHIFT]); v3 *= bf2f(p16[p0.w >> BSHIFT]);
      v4 *= bf2f(p16[p1.x >> BSHIFT]); v5 *= bf2f(p16[p1.y >> BSHIFT]);
      v6 *= bf2f(p16[p1.z >> BSHIFT]); v7 *= bf2f(p16[p1.w >> BSHIFT]);
    }
    atomicAdd(&acc[p0.x & (BNODES - 1)], v0);
    atomicAdd(&acc[p0.y & (BNODES - 1)], v1);
    atomicAdd(&acc[p0.z & (BNODES - 1)], v2);
    atomicAdd(&acc[p0.w & (BNODES - 1)], v3);
    atomicAdd(&acc[p1.x & (BNODES - 1)], v4);
    atomicAdd(&acc[p1.y & (BNODES - 1)], v5);
    atomicAdd(&acc[p1.z & (BNODES - 1)], v6);
    atomicAdd(&acc[p1.w & (BNODES - 1)], v7);
  }
  unsigned rem = n & 7u;                 // scalar tail, threads 0..rem-1
  if (t < rem) {
    unsigned i = s + (n - rem) + t;
    unsigned pk = PK[i];
    float v = bf2f(W16[i]);
    if (mode) v *= bf2f(p16[pk >> BSHIFT]);
    atomicAdd(&acc[pk & (BNODES - 1)], v);
  }
  __syncthreads();

  float* o = out + (size_t)part * N_NODES;
  int base = b * BNODES;
  if (base + BNODES <= N_NODES) {        // full bucket: float4 writeout
    float4* o4 = (float4*)(o + base);
    const float4* a4 = (const float4*)acc;
#pragma unroll
    for (int j = threadIdx.x; j < BNODES / 4; j += ABLK) o4[j] = a4[j];
  } else {
    for (int j = threadIdx.x; base + j < N_NODES; j += ABLK) o[base + j] = acc[j];
  }
}

// ---------------- node-wise kernels ----------------

__global__ void k_dis_p(const float* __restrict__ x, const float* __restrict__ D,
                        float* __restrict__ A, unsigned short* __restrict__ P16,
                        int split) {
  int i = blockIdx.x * blockDim.x + threadIdx.x;
  if (i >= N_NODES) return;
  float deg = 1.0f;                       // self loop
  for (int j = 0; j < split; ++j) deg += D[(size_t)j * N_NODES + i];
  float d = rsqrtf(deg);
  A[i] = d;
  P16[i] = f2bf(d * x[i]);
}

__global__ void k_g2(const float* __restrict__ A, const float* __restrict__ x,
                     const float* __restrict__ D, unsigned short* __restrict__ P16,
                     const float* __restrict__ W1, const float* __restrict__ b1,
                     const float* __restrict__ W2, int split) {
  int i = blockIdx.x * blockDim.x + threadIdx.x;
  if (i >= N_NODES) return;
  float d = A[i];
  float sraw = 0.f;
  for (int j = 0; j < split; ++j) sraw += D[(size_t)j * N_NODES + i];
  float s1 = d * sraw + d * d * x[i];
  float g = 0.f;
#pragma unroll
  for (int j = 0; j < 4; ++j) {
    float h = fmaf(s1, W1[j], b1[j]);
    g = fmaf(fmaxf(h, 0.f), W2[j], g);
  }
  P16[i] = f2bf(d * g);
}

__global__ void k_out2(const float* __restrict__ A,
                       const unsigned short* __restrict__ P16,
                       const float* __restrict__ D, const float* __restrict__ b2,
                       const float* __restrict__ Wl, const float* __restrict__ bl,
                       float* __restrict__ y, int split) {
  int i = blockIdx.x * blockDim.x + threadIdx.x;
  if (i >= N_NODES) return;
  float d = A[i];
  float g = bf2f(P16[i]) / d;             // d in (0,1], safe
  float sraw = 0.f;
  for (int j = 0; j < split; ++j) sraw += D[(size_t)j * N_NODES + i];
  float agg2 = d * sraw + d * d * g;
  float v = fmaf(agg2 + b2[0], Wl[0], bl[0]);
  y[i] = 1.0f / (1.0f + expf(-v));
}

// ---------------- fallback (round-2 global-atomic path) ----------------

__global__ void f_deg(const int* __restrict__ col, const float* __restrict__ ew,
                      float* __restrict__ deg) {
  int i = blockIdx.x * blockDim.x + threadIdx.x;
  int stride = gridDim.x * blockDim.x;
  for (int e = i; e < N_EDGES; e += stride) atomicAdd(&deg[col[e]], ew[e]);
}
__global__ void f_dis(float* __restrict__ a) {
  int i = blockIdx.x * blockDim.x + threadIdx.x;
  if (i < N_NODES) a[i] = rsqrtf(a[i] + 1.0f);
}
__global__ void f_scatter(const int* __restrict__ row, const int* __restrict__ col,
                          const float* __restrict__ ew, const float* __restrict__ dis,
                          const float* __restrict__ src, float* __restrict__ acc) {
  int i = blockIdx.x * blockDim.x + threadIdx.x;
  int stride = gridDim.x * blockDim.x;
  for (int e = i; e < N_EDGES; e += stride) {
    int r = row[e]; int c = col[e];
    atomicAdd(&acc[c], dis[r] * ew[e] * src[r]);
  }
}
__global__ void f_g(const float* __restrict__ dis, const float* __restrict__ x,
                    float* __restrict__ s1g, const float* __restrict__ W1,
                    const float* __restrict__ b1, const float* __restrict__ W2) {
  int i = blockIdx.x * blockDim.x + threadIdx.x;
  if (i >= N_NODES) return;
  float d = dis[i];
  float s1 = d * s1g[i] + d * d * x[i];
  float g = 0.f;
#pragma unroll
  for (int j = 0; j < 4; ++j) {
    float h = fmaf(s1, W1[j], b1[j]);
    g = fmaf(fmaxf(h, 0.f), W2[j], g);
  }
  s1g[i] = g;
}
__global__ void f_out(const float* __restrict__ dis, const float* __restrict__ g,
                      float* __restrict__ s2out, const float* __restrict__ b2,
                      const float* __restrict__ Wl, const float* __restrict__ bl) {
  int i = blockIdx.x * blockDim.x + threadIdx.x;
  if (i >= N_NODES) return;
  float d = dis[i];
  float agg2 = d * s2out[i] + d * d * g[i];
  float v = fmaf(agg2 + b2[0], Wl[0], bl[0]);
  s2out[i] = 1.0f / (1.0f + expf(-v));
}

// ---------------- launch ----------------

extern "C" void kernel_launch(void* const* d_in, const int* in_sizes, int n_in,
                              void* d_out, int out_size, void* d_ws, size_t ws_size,
                              hipStream_t stream) {
  const float* x  = (const float*)d_in[0];
  const int* ei   = (const int*)d_in[1];   // int32 (harness narrows int64)
  const float* ew = (const float*)d_in[2];
  const float* W1 = (const float*)d_in[3];
  const float* b1 = (const float*)d_in[4];
  const float* W2 = (const float*)d_in[5];
  const float* b2 = (const float*)d_in[6];
  const float* Wl = (const float*)d_in[7];
  const float* bl = (const float*)d_in[8];

  const int* row = ei;
  const int* col = ei + N_EDGES;

  auto pad = [](size_t v) { return (v + 255) & ~(size_t)255; };
  const size_t PK_B    = pad((size_t)N_EDGES * 4);         // 64,000,000
  const size_t W16_B   = pad((size_t)N_EDGES * 2);         // 32,000,000
  const size_t HIST_B  = pad((size_t)NHIST_PAD * 4);       // 2,555,904
  const size_t HISTT_B = pad((size_t)NBLK * 256 * 4);      // 2,667,520
  const size_t BSUM_B  = 8192;
  const size_t NODE_B  = pad((size_t)N_NODES * 4);
  const size_t P16_B   = pad((size_t)N_NODES * 2);
  const size_t BASE    = PK_B + W16_B + HIST_B + HISTT_B + BSUM_B + NODE_B + P16_B;

  dim3 blk(256);
  dim3 ngrid((N_NODES + 255) / 256);
  dim3 tgrid((NBLK + 31) / 32, 8);
  dim3 tblk(32, 32);

  int split = 0;
  for (int s : {4, 2, 1})
    if (ws_size >= BASE + (size_t)s * NODE_B) { split = s; break; }

  if (split) {
    char* w = (char*)d_ws;
    unsigned* PK        = (unsigned*)w;
    unsigned short* W16 = (unsigned short*)(w + PK_B);
    unsigned* hist      = (unsigned*)(w + PK_B + W16_B);
    unsigned* histT     = (unsigned*)(w + PK_B + W16_B + HIST_B);  // also histT2
    unsigned* bsum      = (unsigned*)(w + PK_B + W16_B + HIST_B + HISTT_B);
    float* A            = (float*)(w + PK_B + W16_B + HIST_B + HISTT_B + BSUM_B);
    unsigned short* P16 = (unsigned short*)((char*)A + NODE_B);
    float* D            = (float*)((char*)P16 + P16_B);    // split partials

    // zero the scan pad tail (rest of hist fully written by k_t1)
    hipMemsetAsync(hist + NHIST, 0, (size_t)(NHIST_PAD - NHIST) * 4, stream);

    k_count<<<NBLK, FBLK, 0, stream>>>(col, histT);
    k_t1   <<<tgrid, tblk, 0, stream>>>(histT, hist);
    k_scanA<<<NSCAN, SCAN_TPB, 0, stream>>>(hist, bsum);
    k_scanB<<<1, 1024, 0, stream>>>(bsum);
    k_scanC<<<NSCAN, SCAN_TPB, 0, stream>>>(hist, bsum);
    k_t2   <<<tgrid, tblk, 0, stream>>>(hist, histT);      // offsets, transposed
    k_fill <<<NBLK, FBLK, 0, stream>>>(row, col, ew, histT, PK, W16);

    k_acc  <<<NB * split, ABLK, 0, stream>>>(PK, W16, hist, nullptr, D, 0, split);
    k_dis_p<<<ngrid, blk, 0, stream>>>(x, D, A, P16, split);
    k_acc  <<<NB * split, ABLK, 0, stream>>>(PK, W16, hist, P16, D, 1, split);
    k_g2   <<<ngrid, blk, 0, stream>>>(A, x, D, P16, W1, b1, W2, split);
    k_acc  <<<NB * split, ABLK, 0, stream>>>(PK, W16, hist, P16, D, 1, split);
    k_out2 <<<ngrid, blk, 0, stream>>>(A, P16, D, b2, Wl, bl, (float*)d_out, split);
  } else {
    float* Aw = (float*)d_ws;
    float* Bw = Aw + N_NODES;
    float* Cw = (float*)d_out;
    hipMemsetAsync(d_ws, 0, 2ull * N_NODES * 4, stream);
    hipMemsetAsync(d_out, 0, (size_t)N_NODES * 4, stream);
    dim3 egrid(4096);
    f_deg<<<egrid, blk, 0, stream>>>(col, ew, Aw);
    f_dis<<<ngrid, blk, 0, stream>>>(Aw);
    f_scatter<<<egrid, blk, 0, stream>>>(row, col, ew, Aw, x, Bw);
    f_g<<<ngrid, blk, 0, stream>>>(Aw, x, Bw, W1, b1, W2);
    f_scatter<<<egrid, blk, 0, stream>>>(row, col, ew, Aw, Bw, Cw);
    f_out<<<ngrid, blk, 0, stream>>>(Aw, Bw, Cw, b2, Wl, bl);
  }
}

// Round 15
// 309.397 us; speedup vs baseline: 1.3775x; 1.3334x over previous
//
#include <hip/hip_runtime.h>

// GCN on 1M nodes / 16M edges, collapsed to scalar per-node features.
//
//   deg[c]  = sum_{e: col=c} ew[e] + 1 (self loop)
//   dis     = rsqrt(deg)
//   S1[c]   = dis[c] * (sum_e dis[row]*ew*x[row]) + dis[c]^2 * x[c]
//   g[c]    = sum_j relu(S1[c]*W1[j] + b1[j]) * W2[j]
//   S2[c]   = dis[c] * (sum_e dis[row]*ew*g[row]) + dis[c]^2 * g[c]
//   y[c]    = sigmoid((S2[c]+b2)*Wl + bl)
//
// R14 post-mortem: k_acc pinned at ~116us across SEVEN variants = 4.5
// CU-cycles per ds_add_f32 lane-atomic. Falsifying witness: k_count does
// the same 16M LDS atomics as ds_add_u32 (+64MB stream) in ~20us = ~1
// cyc/lane-atomic. f32 LDS atomics are ~5x slower than u32.
// R15: fixed-point accumulator (int LDS + __float2int_rn(v*S), convert at
// writeout). mode0 S=2^22 (deg<=64 -> 8x headroom), mode1 S=2^12 (worst
// |sum|~2e5 < 2^19 range; quant err ~1e-3 << absmax margin). Single change.

constexpr int N_NODES = 1000000;
constexpr int N_EDGES = 16000000;

constexpr int BSHIFT = 12;
constexpr int BNODES = 1 << BSHIFT;                    // 4096 nodes/bucket
constexpr int NB = (N_NODES + BNODES - 1) / BNODES;    // 245 buckets
constexpr int EPT = 12;                                // edges/thread in count+fill
constexpr int FBLK = 512;                              // threads in count+fill
constexpr int CHUNK = FBLK * EPT;                      // 6144 edges/block
constexpr int NBLK = (N_EDGES + CHUNK - 1) / CHUNK;    // 2605
constexpr int NHIST = NB * NBLK;                       // 638,225
constexpr int SCAN_TPB = 256;
constexpr int SCAN_EPB = 1024;
constexpr int NSCAN = (NHIST + SCAN_EPB - 1) / SCAN_EPB;  // 624
constexpr int NHIST_PAD = NSCAN * SCAN_EPB;            // 638,976

__device__ inline unsigned short f2bf(float f) {   // fp32 -> bf16 RNE
  unsigned u = __float_as_uint(f);
  return (unsigned short)((u + 0x7FFFu + ((u >> 16) & 1u)) >> 16);
}
__device__ inline float bf2f(unsigned short h) {
  return __uint_as_float((unsigned)h << 16);
}
// packed-pair bf16 unpack: lo = u<<16 (1 op), hi = u & 0xFFFF0000 (1 op)
__device__ inline float blo(unsigned u) { return __uint_as_float(u << 16); }
__device__ inline float bhi(unsigned u) { return __uint_as_float(u & 0xFFFF0000u); }

// ---------------- build: count / transpose / scan / transpose / fill --------

// histT layout [NBLK][256]: block writes its own contiguous row (coalesced).
__global__ __launch_bounds__(FBLK) void k_count(const int* __restrict__ col,
                                                unsigned* __restrict__ histT) {
  __shared__ unsigned cnt[256];
  int t = threadIdx.x;
  if (t < 256) cnt[t] = 0;
  __syncthreads();
  int e0 = blockIdx.x * CHUNK;
  if (e0 + CHUNK <= N_EDGES) {          // fast path: all loads unguarded
    int c[EPT];
#pragma unroll
    for (int k = 0; k < EPT; ++k) c[k] = col[e0 + k * FBLK + t];
    __builtin_amdgcn_sched_barrier(0);  // keep the load batch issued together
#pragma unroll
    for (int k = 0; k < EPT; ++k) atomicAdd(&cnt[c[k] >> BSHIFT], 1u);
  } else {
#pragma unroll
    for (int k = 0; k < EPT; ++k) {
      int e = e0 + k * FBLK + t;
      if (e < N_EDGES) atomicAdd(&cnt[col[e] >> BSHIFT], 1u);
    }
  }
  __syncthreads();
  if (t < 256) histT[(size_t)blockIdx.x * 256 + t] = cnt[t];
}

// histT[NBLK][256] -> hist[b*NBLK + blk] (bucket-major flat, for linear scan)
__global__ __launch_bounds__(1024) void k_t1(const unsigned* __restrict__ in,
                                             unsigned* __restrict__ out) {
  __shared__ unsigned tile[32][33];
  int bx = blockIdx.x * 32;   // blk base
  int by = blockIdx.y * 32;   // b base
  int tx = threadIdx.x, ty = threadIdx.y;
  int rblk = bx + ty;
  if (rblk < NBLK) tile[ty][tx] = in[(size_t)rblk * 256 + by + tx];
  __syncthreads();
  int wb = by + ty, wblk = bx + tx;
  if (wb < NB && wblk < NBLK) out[(size_t)wb * NBLK + wblk] = tile[tx][ty];
}

// hist offsets (bucket-major) -> histT2[blk*256 + b] (fill reads coalesced)
__global__ __launch_bounds__(1024) void k_t2(const unsigned* __restrict__ in,
                                             unsigned* __restrict__ out) {
  __shared__ unsigned tile[32][33];
  int bx = blockIdx.x * 32;   // blk base
  int by = blockIdx.y * 32;   // b base
  int tx = threadIdx.x, ty = threadIdx.y;
  int rb = by + ty, rblk = bx + tx;
  if (rb < NB && rblk < NBLK) tile[ty][tx] = in[(size_t)rb * NBLK + rblk];
  __syncthreads();
  int wblk = bx + ty, wb = by + tx;
  if (wblk < NBLK && wb < NB) out[(size_t)wblk * 256 + wb] = tile[tx][ty];
}

__global__ __launch_bounds__(SCAN_TPB) void k_scanA(unsigned* __restrict__ h,
                                                    unsigned* __restrict__ bsum) {
  __shared__ unsigned sc[SCAN_TPB];
  int t = threadIdx.x;
  size_t base = (size_t)blockIdx.x * SCAN_EPB + (size_t)t * 4;
  uint4 v = *(const uint4*)(h + base);
  unsigned s = v.x + v.y + v.z + v.w;
  sc[t] = s;
  __syncthreads();
  for (int d = 1; d < SCAN_TPB; d <<= 1) {
    unsigned u = (t >= d) ? sc[t - d] : 0;
    __syncthreads();
    sc[t] += u;
    __syncthreads();
  }
  unsigned ex = sc[t] - s;
  uint4 o;
  o.x = ex; o.y = ex + v.x; o.z = ex + v.x + v.y; o.w = ex + v.x + v.y + v.z;
  *(uint4*)(h + base) = o;
  if (t == SCAN_TPB - 1) bsum[blockIdx.x] = sc[t];
}

__global__ __launch_bounds__(1024) void k_scanB(unsigned* __restrict__ bsum) {
  __shared__ unsigned sc[1024];
  int t = threadIdx.x;
  unsigned a0 = (2 * t < NSCAN) ? bsum[2 * t] : 0;
  unsigned a1 = (2 * t + 1 < NSCAN) ? bsum[2 * t + 1] : 0;
  unsigned s = a0 + a1;
  sc[t] = s;
  __syncthreads();
  for (int d = 1; d < 1024; d <<= 1) {
    unsigned u = (t >= d) ? sc[t - d] : 0;
    __syncthreads();
    sc[t] += u;
    __syncthreads();
  }
  unsigned ex = sc[t] - s;
  if (2 * t < NSCAN) bsum[2 * t] = ex;
  if (2 * t + 1 < NSCAN) bsum[2 * t + 1] = ex + a0;
}

__global__ __launch_bounds__(SCAN_TPB) void k_scanC(unsigned* __restrict__ h,
                                                    const unsigned* __restrict__ bsum) {
  unsigned add = bsum[blockIdx.x];
  size_t base = (size_t)blockIdx.x * SCAN_EPB + (size_t)threadIdx.x * 4;
  uint4 v = *(uint4*)(h + base);
  v.x += add; v.y += add; v.z += add; v.w += add;
  *(uint4*)(h + base) = v;
}

// Register-stash + LDS-reorder fill, SoA output: PK (u32) + W16 (bf16).
// pk = row<<12 | col&0xFFF; row < 2^20 fits.
__global__ __launch_bounds__(FBLK) void k_fill(const int* __restrict__ row,
                                               const int* __restrict__ col,
                                               const float* __restrict__ ew,
                                               const unsigned* __restrict__ histT2,
                                               unsigned* __restrict__ PK,
                                               unsigned short* __restrict__ W16) {
  __shared__ unsigned lhist[FBLK];
  __shared__ unsigned lb[FBLK];
  __shared__ unsigned tail[FBLK];
  __shared__ unsigned gbase[NB];
  __shared__ unsigned wsum[FBLK / 64];
  __shared__ unsigned spk[CHUNK];          // 24KB
  __shared__ unsigned short sw[CHUNK];     // 12KB
  __shared__ unsigned short sbkt[CHUNK];   // 12KB

  int t = threadIdx.x;
  int blk = blockIdx.x;
  lhist[t] = 0;
  if (t < NB) gbase[t] = histT2[(size_t)blk * 256 + t];  // coalesced row read
  __syncthreads();                                        // B1

  int e0 = blk * CHUNK;
  unsigned pk[EPT];
  unsigned short wv[EPT];
  int bk[EPT];
  if (e0 + CHUNK <= N_EDGES) {          // fast path (2604 of 2605 blocks)
    int cv[EPT], rv[EPT];
    float wf[EPT];
#pragma unroll
    for (int k = 0; k < EPT; ++k) {
      int e = e0 + k * FBLK + t;
      cv[k] = col[e];
      rv[k] = row[e];
      wf[k] = ew[e];
    }
    __builtin_amdgcn_sched_barrier(0);  // 36 loads in flight before any use
#pragma unroll
    for (int k = 0; k < EPT; ++k) {
      pk[k] = ((unsigned)rv[k] << BSHIFT) | (unsigned)(cv[k] & (BNODES - 1));
      wv[k] = f2bf(wf[k]);
      bk[k] = cv[k] >> BSHIFT;
    }
#pragma unroll
    for (int k = 0; k < EPT; ++k) atomicAdd(&lhist[bk[k]], 1u);
  } else {
#pragma unroll
    for (int k = 0; k < EPT; ++k) {
      int e = e0 + k * FBLK + t;
      bk[k] = -1;
      if (e < N_EDGES) {
        int c = col[e];
        pk[k] = ((unsigned)row[e] << BSHIFT) | (unsigned)(c & (BNODES - 1));
        wv[k] = f2bf(ew[e]);
        bk[k] = c >> BSHIFT;
        atomicAdd(&lhist[bk[k]], 1u);
      }
    }
  }
  __syncthreads();                                        // B2

  // exclusive prefix over FBLK bucket counts: wave scan + 8-entry fixup
  unsigned own = lhist[t];
  unsigned v = own;
#pragma unroll
  for (int d = 1; d < 64; d <<= 1) {
    unsigned u = __shfl_up(v, d, 64);
    if ((t & 63) >= d) v += u;
  }
  if ((t & 63) == 63) wsum[t >> 6] = v;
  __syncthreads();                                        // B3
  unsigned wbase = 0;
  unsigned total = 0;
#pragma unroll
  for (int w = 0; w < FBLK / 64; ++w) {
    if (w < (t >> 6)) wbase += wsum[w];
    total += wsum[w];
  }
  unsigned ex = wbase + v - own;
  lb[t] = ex;
  tail[t] = ex;
  __syncthreads();                                        // B4

  if (e0 + CHUNK <= N_EDGES) {
#pragma unroll
    for (int k = 0; k < EPT; ++k) {
      unsigned s = atomicAdd(&tail[bk[k]], 1u);
      spk[s] = pk[k];
      sw[s] = wv[k];
      sbkt[s] = (unsigned short)bk[k];
    }
  } else {
#pragma unroll
    for (int k = 0; k < EPT; ++k) {
      if (bk[k] >= 0) {
        unsigned s = atomicAdd(&tail[bk[k]], 1u);
        spk[s] = pk[k];
        sw[s] = wv[k];
        sbkt[s] = (unsigned short)bk[k];
      }
    }
  }
  __syncthreads();                                        // B5

  // staged order is bucket-sorted: consecutive s -> consecutive global dest.
  unsigned s = t;
  for (; s + 3u * FBLK < total; s += 4u * FBLK) {
#pragma unroll
    for (int u = 0; u < 4; ++u) {
      unsigned si = s + u * FBLK;
      unsigned b = sbkt[si];
      unsigned idx = gbase[b] + (si - lb[b]);
      PK[idx] = spk[si];
      W16[idx] = sw[si];
    }
  }
  for (; s < total; s += FBLK) {
    unsigned b = sbkt[s];
    unsigned idx = gbase[b] + (s - lb[b]);
    PK[idx] = spk[s];
    W16[idx] = sw[s];
  }
}

// ---------------- accumulate: one (bucket,part) per block ----------------
// mode 0: val = ew. mode 1: val = ew * bf16 p16[row].
// FIXED-POINT LDS accumulator: ds_add_u32 is ~5x faster than ds_add_f32
// (evidence: k_count's 16M u32 atomics ~20us vs k_acc's 16M f32 ~116us).
// acc[i] += round(v * FS); writeout converts back with INV = 1/FS.
constexpr int ABLK = 512;

__global__ __launch_bounds__(ABLK) void k_acc(const unsigned* __restrict__ PK,
                                              const unsigned short* __restrict__ W16,
                                              const unsigned* __restrict__ hist,
                                              const unsigned short* __restrict__ p16,
                                              float* __restrict__ out,
                                              int mode, int split,
                                              float FS, float INV) {
  __shared__ int acc[BNODES];
  {
    int4* a4 = (int4*)acc;
#pragma unroll
    for (int i = threadIdx.x; i < BNODES / 4; i += ABLK)
      a4[i] = make_int4(0, 0, 0, 0);
  }
  __syncthreads();
  int b = blockIdx.x / split;
  int part = blockIdx.x - b * split;
  unsigned bs = hist[(size_t)b * NBLK];
  unsigned be = (b + 1 < NB) ? hist[(size_t)(b + 1) * NBLK] : (unsigned)N_EDGES;
  unsigned len = be - bs;
  unsigned s = bs + (unsigned)(((unsigned long long)len * part) / split);
  unsigned e = bs + (unsigned)(((unsigned long long)len * (part + 1)) / split);
  unsigned t = threadIdx.x;

  unsigned s_al = (s + 7u) & ~7u;        // align to 8 records
  if (s_al > e) s_al = e;
  if (t == 0) {                          // scalar head (<8 records)
    for (unsigned i = s; i < s_al; ++i) {
      unsigned pk = PK[i];
      float v = bf2f(W16[i]);
      if (mode) v *= bf2f(p16[pk >> BSHIFT]);
      atomicAdd(&acc[pk & (BNODES - 1)], __float2int_rn(v * FS));
    }
  }
  s = s_al;
  unsigned n = (e > s) ? (e - s) : 0u;
  unsigned ng = n >> 3;                  // groups of 8 records
  const uint4* pk4 = (const uint4*)(PK + s);    // group g: pk4[2g], pk4[2g+1]
  const uint4* w4  = (const uint4*)(W16 + s);   // group g: w4[g] (8 bf16)

  unsigned ip = t;
  for (; ip + ABLK < ng; ip += 2u * ABLK) {     // 2 groups = 16 records
    unsigned g1 = ip + ABLK;
    uint4 pA0 = pk4[2u * ip], pA1 = pk4[2u * ip + 1u];
    uint4 pB0 = pk4[2u * g1], pB1 = pk4[2u * g1 + 1u];
    uint4 wA = w4[ip], wB = w4[g1];
    __builtin_amdgcn_sched_barrier(0);   // 6 loads issued before any use
    if (mode) {
      unsigned short gA0 = p16[pA0.x >> BSHIFT], gA1 = p16[pA0.y >> BSHIFT];
      unsigned short gA2 = p16[pA0.z >> BSHIFT], gA3 = p16[pA0.w >> BSHIFT];
      unsigned short gA4 = p16[pA1.x >> BSHIFT], gA5 = p16[pA1.y >> BSHIFT];
      unsigned short gA6 = p16[pA1.z >> BSHIFT], gA7 = p16[pA1.w >> BSHIFT];
      unsigned short gB0 = p16[pB0.x >> BSHIFT], gB1 = p16[pB0.y >> BSHIFT];
      unsigned short gB2 = p16[pB0.z >> BSHIFT], gB3 = p16[pB0.w >> BSHIFT];
      unsigned short gB4 = p16[pB1.x >> BSHIFT], gB5 = p16[pB1.y >> BSHIFT];
      unsigned short gB6 = p16[pB1.z >> BSHIFT], gB7 = p16[pB1.w >> BSHIFT];
      __builtin_amdgcn_sched_barrier(0); // 16 gathers in flight before use
      atomicAdd(&acc[pA0.x & (BNODES - 1)], __float2int_rn(blo(wA.x) * bf2f(gA0) * FS));
      atomicAdd(&acc[pA0.y & (BNODES - 1)], __float2int_rn(bhi(wA.x) * bf2f(gA1) * FS));
      atomicAdd(&acc[pA0.z & (BNODES - 1)], __float2int_rn(blo(wA.y) * bf2f(gA2) * FS));
      atomicAdd(&acc[pA0.w & (BNODES - 1)], __float2int_rn(bhi(wA.y) * bf2f(gA3) * FS));
      atomicAdd(&acc[pA1.x & (BNODES - 1)], __float2int_rn(blo(wA.z) * bf2f(gA4) * FS));
      atomicAdd(&acc[pA1.y & (BNODES - 1)], __float2int_rn(bhi(wA.z) * bf2f(gA5) * FS));
      atomicAdd(&acc[pA1.z & (BNODES - 1)], __float2int_rn(blo(wA.w) * bf2f(gA6) * FS));
      atomicAdd(&acc[pA1.w & (BNODES - 1)], __float2int_rn(bhi(wA.w) * bf2f(gA7) * FS));
      atomicAdd(&acc[pB0.x & (BNODES - 1)], __float2int_rn(blo(wB.x) * bf2f(gB0) * FS));
      atomicAdd(&acc[pB0.y & (BNODES - 1)], __float2int_rn(bhi(wB.x) * bf2f(gB1) * FS));
      atomicAdd(&acc[pB0.z & (BNODES - 1)], __float2int_rn(blo(wB.y) * bf2f(gB2) * FS));
      atomicAdd(&acc[pB0.w & (BNODES - 1)], __float2int_rn(bhi(wB.y) * bf2f(gB3) * FS));
      atomicAdd(&acc[pB1.x & (BNODES - 1)], __float2int_rn(blo(wB.z) * bf2f(gB4) * FS));
      atomicAdd(&acc[pB1.y & (BNODES - 1)], __float2int_rn(bhi(wB.z) * bf2f(gB5) * FS));
      atomicAdd(&acc[pB1.z & (BNODES - 1)], __float2int_rn(blo(wB.w) * bf2f(gB6) * FS));
      atomicAdd(&acc[pB1.w & (BNODES - 1)], __float2int_rn(bhi(wB.w) * bf2f(gB7) * FS));
    } else {
      atomicAdd(&acc[pA0.x & (BNODES - 1)], __float2int_rn(blo(wA.x) * FS));
      atomicAdd(&acc[pA0.y & (BNODES - 1)], __float2int_rn(bhi(wA.x) * FS));
      atomicAdd(&acc[pA0.z & (BNODES - 1)], __float2int_rn(blo(wA.y) * FS));
      atomicAdd(&acc[pA0.w & (BNODES - 1)], __float2int_rn(bhi(wA.y) * FS));
      atomicAdd(&acc[pA1.x & (BNODES - 1)], __float2int_rn(blo(wA.z) * FS));
      atomicAdd(&acc[pA1.y & (BNODES - 1)], __float2int_rn(bhi(wA.z) * FS));
      atomicAdd(&acc[pA1.z & (BNODES - 1)], __float2int_rn(blo(wA.w) * FS));
      atomicAdd(&acc[pA1.w & (BNODES - 1)], __float2int_rn(bhi(wA.w) * FS));
      atomicAdd(&acc[pB0.x & (BNODES - 1)], __float2int_rn(blo(wB.x) * FS));
      atomicAdd(&acc[pB0.y & (BNODES - 1)], __float2int_rn(bhi(wB.x) * FS));
      atomicAdd(&acc[pB0.z & (BNODES - 1)], __float2int_rn(blo(wB.y) * FS));
      atomicAdd(&acc[pB0.w & (BNODES - 1)], __float2int_rn(bhi(wB.y) * FS));
      atomicAdd(&acc[pB1.x & (BNODES - 1)], __float2int_rn(blo(wB.z) * FS));
      atomicAdd(&acc[pB1.y & (BNODES - 1)], __float2int_rn(bhi(wB.z) * FS));
      atomicAdd(&acc[pB1.z & (BNODES - 1)], __float2int_rn(blo(wB.w) * FS));
      atomicAdd(&acc[pB1.w & (BNODES - 1)], __float2int_rn(bhi(wB.w) * FS));
    }
  }
  for (; ip < ng; ip += 2u * ABLK) {     // leftover single group (8 records)
    uint4 p0 = pk4[2u * ip], p1 = pk4[2u * ip + 1u];
    uint4 w = w4[ip];
    float v0 = blo(w.x), v1 = bhi(w.x), v2 = blo(w.y), v3 = bhi(w.y);
    float v4 = blo(w.z), v5 = bhi(w.z), v6 = blo(w.w), v7 = bhi(w.w);
    if (mode) {
      v0 *= bf2f(p16[p0.x >> BSHIFT]); v1 *= bf2f(p16[p0.y >> BSHIFT]);
      v2 *= bf2f(p16[p0.z >> BSHIFT]); v3 *= bf2f(p16[p0.w >> BSHIFT]);
      v4 *= bf2f(p16[p1.x >> BSHIFT]); v5 *= bf2f(p16[p1.y >> BSHIFT]);
      v6 *= bf2f(p16[p1.z >> BSHIFT]); v7 *= bf2f(p16[p1.w >> BSHIFT]);
    }
    atomicAdd(&acc[p0.x & (BNODES - 1)], __float2int_rn(v0 * FS));
    atomicAdd(&acc[p0.y & (BNODES - 1)], __float2int_rn(v1 * FS));
    atomicAdd(&acc[p0.z & (BNODES - 1)], __float2int_rn(v2 * FS));
    atomicAdd(&acc[p0.w & (BNODES - 1)], __float2int_rn(v3 * FS));
    atomicAdd(&acc[p1.x & (BNODES - 1)], __float2int_rn(v4 * FS));
    atomicAdd(&acc[p1.y & (BNODES - 1)], __float2int_rn(v5 * FS));
    atomicAdd(&acc[p1.z & (BNODES - 1)], __float2int_rn(v6 * FS));
    atomicAdd(&acc[p1.w & (BNODES - 1)], __float2int_rn(v7 * FS));
  }
  unsigned rem = n & 7u;                 // scalar tail, threads 0..rem-1
  if (t < rem) {
    unsigned i = s + (n - rem) + t;
    unsigned pk = PK[i];
    float v = bf2f(W16[i]);
    if (mode) v *= bf2f(p16[pk >> BSHIFT]);
    atomicAdd(&acc[pk & (BNODES - 1)], __float2int_rn(v * FS));
  }
  __syncthreads();

  float* o = out + (size_t)part * N_NODES;
  int base = b * BNODES;
  if (base + BNODES <= N_NODES) {        // full bucket: float4 writeout
    float4* o4 = (float4*)(o + base);
    const int4* a4 = (const int4*)acc;
#pragma unroll
    for (int j = threadIdx.x; j < BNODES / 4; j += ABLK) {
      int4 q = a4[j];
      o4[j] = make_float4((float)q.x * INV, (float)q.y * INV,
                          (float)q.z * INV, (float)q.w * INV);
    }
  } else {
    for (int j = threadIdx.x; base + j < N_NODES; j += ABLK)
      o[base + j] = (float)acc[j] * INV;
  }
}

// ---------------- node-wise kernels ----------------

__global__ void k_dis_p(const float* __restrict__ x, const float* __restrict__ D,
                        float* __restrict__ A, unsigned short* __restrict__ P16,
                        int split) {
  int i = blockIdx.x * blockDim.x + threadIdx.x;
  if (i >= N_NODES) return;
  float deg = 1.0f;                       // self loop
  for (int j = 0; j < split; ++j) deg += D[(size_t)j * N_NODES + i];
  float d = rsqrtf(deg);
  A[i] = d;
  P16[i] = f2bf(d * x[i]);
}

__global__ void k_g2(const float* __restrict__ A, const float* __restrict__ x,
                     const float* __restrict__ D, unsigned short* __restrict__ P16,
                     const float* __restrict__ W1, const float* __restrict__ b1,
                     const float* __restrict__ W2, int split) {
  int i = blockIdx.x * blockDim.x + threadIdx.x;
  if (i >= N_NODES) return;
  float d = A[i];
  float sraw = 0.f;
  for (int j = 0; j < split; ++j) sraw += D[(size_t)j * N_NODES + i];
  float s1 = d * sraw + d * d * x[i];
  float g = 0.f;
#pragma unroll
  for (int j = 0; j < 4; ++j) {
    float h = fmaf(s1, W1[j], b1[j]);
    g = fmaf(fmaxf(h, 0.f), W2[j], g);
  }
  P16[i] = f2bf(d * g);
}

__global__ void k_out2(const float* __restrict__ A,
                       const unsigned short* __restrict__ P16,
                       const float* __restrict__ D, const float* __restrict__ b2,
                       const float* __restrict__ Wl, const float* __restrict__ bl,
                       float* __restrict__ y, int split) {
  int i = blockIdx.x * blockDim.x + threadIdx.x;
  if (i >= N_NODES) return;
  float d = A[i];
  float g = bf2f(P16[i]) / d;             // d in (0,1], safe
  float sraw = 0.f;
  for (int j = 0; j < split; ++j) sraw += D[(size_t)j * N_NODES + i];
  float agg2 = d * sraw + d * d * g;
  float v = fmaf(agg2 + b2[0], Wl[0], bl[0]);
  y[i] = 1.0f / (1.0f + expf(-v));
}

// ---------------- fallback (round-2 global-atomic path) ----------------

__global__ void f_deg(const int* __restrict__ col, const float* __restrict__ ew,
                      float* __restrict__ deg) {
  int i = blockIdx.x * blockDim.x + threadIdx.x;
  int stride = gridDim.x * blockDim.x;
  for (int e = i; e < N_EDGES; e += stride) atomicAdd(&deg[col[e]], ew[e]);
}
__global__ void f_dis(float* __restrict__ a) {
  int i = blockIdx.x * blockDim.x + threadIdx.x;
  if (i < N_NODES) a[i] = rsqrtf(a[i] + 1.0f);
}
__global__ void f_scatter(const int* __restrict__ row, const int* __restrict__ col,
                          const float* __restrict__ ew, const float* __restrict__ dis,
                          const float* __restrict__ src, float* __restrict__ acc) {
  int i = blockIdx.x * blockDim.x + threadIdx.x;
  int stride = gridDim.x * blockDim.x;
  for (int e = i; e < N_EDGES; e += stride) {
    int r = row[e]; int c = col[e];
    atomicAdd(&acc[c], dis[r] * ew[e] * src[r]);
  }
}
__global__ void f_g(const float* __restrict__ dis, const float* __restrict__ x,
                    float* __restrict__ s1g, const float* __restrict__ W1,
                    const float* __restrict__ b1, const float* __restrict__ W2) {
  int i = blockIdx.x * blockDim.x + threadIdx.x;
  if (i >= N_NODES) return;
  float d = dis[i];
  float s1 = d * s1g[i] + d * d * x[i];
  float g = 0.f;
#pragma unroll
  for (int j = 0; j < 4; ++j) {
    float h = fmaf(s1, W1[j], b1[j]);
    g = fmaf(fmaxf(h, 0.f), W2[j], g);
  }
  s1g[i] = g;
}
__global__ void f_out(const float* __restrict__ dis, const float* __restrict__ g,
                      float* __restrict__ s2out, const float* __restrict__ b2,
                      const float* __restrict__ Wl, const float* __restrict__ bl) {
  int i = blockIdx.x * blockDim.x + threadIdx.x;
  if (i >= N_NODES) return;
  float d = dis[i];
  float agg2 = d * s2out[i] + d * d * g[i];
  float v = fmaf(agg2 + b2[0], Wl[0], bl[0]);
  s2out[i] = 1.0f / (1.0f + expf(-v));
}

// ---------------- launch ----------------

extern "C" void kernel_launch(void* const* d_in, const int* in_sizes, int n_in,
                              void* d_out, int out_size, void* d_ws, size_t ws_size,
                              hipStream_t stream) {
  const float* x  = (const float*)d_in[0];
  const int* ei   = (const int*)d_in[1];   // int32 (harness narrows int64)
  const float* ew = (const float*)d_in[2];
  const float* W1 = (const float*)d_in[3];
  const float* b1 = (const float*)d_in[4];
  const float* W2 = (const float*)d_in[5];
  const float* b2 = (const float*)d_in[6];
  const float* Wl = (const float*)d_in[7];
  const float* bl = (const float*)d_in[8];

  const int* row = ei;
  const int* col = ei + N_EDGES;

  auto pad = [](size_t v) { return (v + 255) & ~(size_t)255; };
  const size_t PK_B    = pad((size_t)N_EDGES * 4);         // 64,000,000
  const size_t W16_B   = pad((size_t)N_EDGES * 2);         // 32,000,000
  const size_t HIST_B  = pad((size_t)NHIST_PAD * 4);       // 2,555,904
  const size_t HISTT_B = pad((size_t)NBLK * 256 * 4);      // 2,667,520
  const size_t BSUM_B  = 8192;
  const size_t NODE_B  = pad((size_t)N_NODES * 4);
  const size_t P16_B   = pad((size_t)N_NODES * 2);
  const size_t BASE    = PK_B + W16_B + HIST_B + HISTT_B + BSUM_B + NODE_B + P16_B;

  dim3 blk(256);
  dim3 ngrid((N_NODES + 255) / 256);
  dim3 tgrid((NBLK + 31) / 32, 8);
  dim3 tblk(32, 32);

  // fixed-point scales: deg <= 64 -> 2^22 (max 2^28); s1/s2 worst |sum| ~2e5
  // -> 2^12 (range +-2^19 after sum; resolution 2.4e-4 << absmax margin)
  const float FS0 = 4194304.f, INV0 = 1.f / 4194304.f;
  const float FS1 = 4096.f,    INV1 = 1.f / 4096.f;

  int split = 0;
  for (int s : {4, 2, 1})
    if (ws_size >= BASE + (size_t)s * NODE_B) { split = s; break; }

  if (split) {
    char* w = (char*)d_ws;
    unsigned* PK        = (unsigned*)w;
    unsigned short* W16 = (unsigned short*)(w + PK_B);
    unsigned* hist      = (unsigned*)(w + PK_B + W16_B);
    unsigned* histT     = (unsigned*)(w + PK_B + W16_B + HIST_B);  // also histT2
    unsigned* bsum      = (unsigned*)(w + PK_B + W16_B + HIST_B + HISTT_B);
    float* A            = (float*)(w + PK_B + W16_B + HIST_B + HISTT_B + BSUM_B);
    unsigned short* P16 = (unsigned short*)((char*)A + NODE_B);
    float* D            = (float*)((char*)P16 + P16_B);    // split partials

    // zero the scan pad tail (rest of hist fully written by k_t1)
    hipMemsetAsync(hist + NHIST, 0, (size_t)(NHIST_PAD - NHIST) * 4, stream);

    k_count<<<NBLK, FBLK, 0, stream>>>(col, histT);
    k_t1   <<<tgrid, tblk, 0, stream>>>(histT, hist);
    k_scanA<<<NSCAN, SCAN_TPB, 0, stream>>>(hist, bsum);
    k_scanB<<<1, 1024, 0, stream>>>(bsum);
    k_scanC<<<NSCAN, SCAN_TPB, 0, stream>>>(hist, bsum);
    k_t2   <<<tgrid, tblk, 0, stream>>>(hist, histT);      // offsets, transposed
    k_fill <<<NBLK, FBLK, 0, stream>>>(row, col, ew, histT, PK, W16);

    k_acc  <<<NB * split, ABLK, 0, stream>>>(PK, W16, hist, nullptr, D, 0, split, FS0, INV0);
    k_dis_p<<<ngrid, blk, 0, stream>>>(x, D, A, P16, split);
    k_acc  <<<NB * split, ABLK, 0, stream>>>(PK, W16, hist, P16, D, 1, split, FS1, INV1);
    k_g2   <<<ngrid, blk, 0, stream>>>(A, x, D, P16, W1, b1, W2, split);
    k_acc  <<<NB * split, ABLK, 0, stream>>>(PK, W16, hist, P16, D, 1, split, FS1, INV1);
    k_out2 <<<ngrid, blk, 0, stream>>>(A, P16, D, b2, Wl, bl, (float*)d_out, split);
  } else {
    float* Aw = (float*)d_ws;
    float* Bw = Aw + N_NODES;
    float* Cw = (float*)d_out;
    hipMemsetAsync(d_ws, 0, 2ull * N_NODES * 4, stream);
    hipMemsetAsync(d_out, 0, (size_t)N_NODES * 4, stream);
    dim3 egrid(4096);
    f_deg<<<egrid, blk, 0, stream>>>(col, ew, Aw);
    f_dis<<<ngrid, blk, 0, stream>>>(Aw);
    f_scatter<<<egrid, blk, 0, stream>>>(row, col, ew, Aw, x, Bw);
    f_g<<<ngrid, blk, 0, stream>>>(Aw, x, Bw, W1, b1, W2);
    f_scatter<<<egrid, blk, 0, stream>>>(row, col, ew, Aw, Bw, Cw);
    f_out<<<ngrid, blk, 0, stream>>>(Aw, Bw, Cw, b2, Wl, bl);
  }
}

// Round 16
// 308.714 us; speedup vs baseline: 1.3805x; 1.0022x over previous
//
#include <hip/hip_runtime.h>

// GCN on 1M nodes / 16M edges, collapsed to scalar per-node features.
//
//   deg[c]  = sum_{e: col=c} ew[e] + 1 (self loop)
//   dis     = rsqrt(deg)
//   S1[c]   = dis[c] * (sum_e dis[row]*ew*x[row]) + dis[c]^2 * x[c]
//   g[c]    = sum_j relu(S1[c]*W1[j] + b1[j]) * W2[j]
//   S2[c]   = dis[c] * (sum_e dis[row]*ew*g[row]) + dis[c]^2 * g[c]
//   y[c]    = sigmoid((S2[c]+b2)*Wl + bl)
//
// R15 post-mortem: fixed-point LDS atomics cut acc 116->~50us (ds_add_u32
// ~5x ds_add_f32 confirmed). k_fill now dominates at ~100us with 34%
// occupancy (56KB LDS -> 16/32 waves) and a 5-barrier dependency chain.
// R16: fill at 1024thr x EPT6 (CHUNK 6144 unchanged -> same write runs,
// same hist), uchar sbkt (-6KB), 256-entry scan tables (-3KB) -> 47KB LDS,
// 2 blocks x 16 waves = 32 waves/CU (100%). Single-variable change.

constexpr int N_NODES = 1000000;
constexpr int N_EDGES = 16000000;

constexpr int BSHIFT = 12;
constexpr int BNODES = 1 << BSHIFT;                    // 4096 nodes/bucket
constexpr int NB = (N_NODES + BNODES - 1) / BNODES;    // 245 buckets
constexpr int FBLK_C = 512;                            // count threads
constexpr int EPT_C = 12;
constexpr int FBLK_F = 1024;                           // fill threads
constexpr int EPT_F = 6;
constexpr int CHUNK = FBLK_C * EPT_C;                  // 6144 (== FBLK_F*EPT_F)
constexpr int NBLK = (N_EDGES + CHUNK - 1) / CHUNK;    // 2605
constexpr int NHIST = NB * NBLK;                       // 638,225
constexpr int SCAN_TPB = 256;
constexpr int SCAN_EPB = 1024;
constexpr int NSCAN = (NHIST + SCAN_EPB - 1) / SCAN_EPB;  // 624
constexpr int NHIST_PAD = NSCAN * SCAN_EPB;            // 638,976

__device__ inline unsigned short f2bf(float f) {   // fp32 -> bf16 RNE
  unsigned u = __float_as_uint(f);
  return (unsigned short)((u + 0x7FFFu + ((u >> 16) & 1u)) >> 16);
}
__device__ inline float bf2f(unsigned short h) {
  return __uint_as_float((unsigned)h << 16);
}
// packed-pair bf16 unpack: lo = u<<16 (1 op), hi = u & 0xFFFF0000 (1 op)
__device__ inline float blo(unsigned u) { return __uint_as_float(u << 16); }
__device__ inline float bhi(unsigned u) { return __uint_as_float(u & 0xFFFF0000u); }

// ---------------- build: count / transpose / scan / transpose / fill --------

// histT layout [NBLK][256]: block writes its own contiguous row (coalesced).
__global__ __launch_bounds__(FBLK_C) void k_count(const int* __restrict__ col,
                                                  unsigned* __restrict__ histT) {
  __shared__ unsigned cnt[256];
  int t = threadIdx.x;
  if (t < 256) cnt[t] = 0;
  __syncthreads();
  int e0 = blockIdx.x * CHUNK;
  if (e0 + CHUNK <= N_EDGES) {          // fast path: all loads unguarded
    int c[EPT_C];
#pragma unroll
    for (int k = 0; k < EPT_C; ++k) c[k] = col[e0 + k * FBLK_C + t];
    __builtin_amdgcn_sched_barrier(0);  // keep the load batch issued together
#pragma unroll
    for (int k = 0; k < EPT_C; ++k) atomicAdd(&cnt[c[k] >> BSHIFT], 1u);
  } else {
#pragma unroll
    for (int k = 0; k < EPT_C; ++k) {
      int e = e0 + k * FBLK_C + t;
      if (e < N_EDGES) atomicAdd(&cnt[col[e] >> BSHIFT], 1u);
    }
  }
  __syncthreads();
  if (t < 256) histT[(size_t)blockIdx.x * 256 + t] = cnt[t];
}

// histT[NBLK][256] -> hist[b*NBLK + blk] (bucket-major flat, for linear scan)
__global__ __launch_bounds__(1024) void k_t1(const unsigned* __restrict__ in,
                                             unsigned* __restrict__ out) {
  __shared__ unsigned tile[32][33];
  int bx = blockIdx.x * 32;   // blk base
  int by = blockIdx.y * 32;   // b base
  int tx = threadIdx.x, ty = threadIdx.y;
  int rblk = bx + ty;
  if (rblk < NBLK) tile[ty][tx] = in[(size_t)rblk * 256 + by + tx];
  __syncthreads();
  int wb = by + ty, wblk = bx + tx;
  if (wb < NB && wblk < NBLK) out[(size_t)wb * NBLK + wblk] = tile[tx][ty];
}

// hist offsets (bucket-major) -> histT2[blk*256 + b] (fill reads coalesced)
__global__ __launch_bounds__(1024) void k_t2(const unsigned* __restrict__ in,
                                             unsigned* __restrict__ out) {
  __shared__ unsigned tile[32][33];
  int bx = blockIdx.x * 32;   // blk base
  int by = blockIdx.y * 32;   // b base
  int tx = threadIdx.x, ty = threadIdx.y;
  int rb = by + ty, rblk = bx + tx;
  if (rb < NB && rblk < NBLK) tile[ty][tx] = in[(size_t)rb * NBLK + rblk];
  __syncthreads();
  int wblk = bx + ty, wb = by + tx;
  if (wblk < NBLK && wb < NB) out[(size_t)wblk * 256 + wb] = tile[tx][ty];
}

__global__ __launch_bounds__(SCAN_TPB) void k_scanA(unsigned* __restrict__ h,
                                                    unsigned* __restrict__ bsum) {
  __shared__ unsigned sc[SCAN_TPB];
  int t = threadIdx.x;
  size_t base = (size_t)blockIdx.x * SCAN_EPB + (size_t)t * 4;
  uint4 v = *(const uint4*)(h + base);
  unsigned s = v.x + v.y + v.z + v.w;
  sc[t] = s;
  __syncthreads();
  for (int d = 1; d < SCAN_TPB; d <<= 1) {
    unsigned u = (t >= d) ? sc[t - d] : 0;
    __syncthreads();
    sc[t] += u;
    __syncthreads();
  }
  unsigned ex = sc[t] - s;
  uint4 o;
  o.x = ex; o.y = ex + v.x; o.z = ex + v.x + v.y; o.w = ex + v.x + v.y + v.z;
  *(uint4*)(h + base) = o;
  if (t == SCAN_TPB - 1) bsum[blockIdx.x] = sc[t];
}

__global__ __launch_bounds__(1024) void k_scanB(unsigned* __restrict__ bsum) {
  __shared__ unsigned sc[1024];
  int t = threadIdx.x;
  unsigned a0 = (2 * t < NSCAN) ? bsum[2 * t] : 0;
  unsigned a1 = (2 * t + 1 < NSCAN) ? bsum[2 * t + 1] : 0;
  unsigned s = a0 + a1;
  sc[t] = s;
  __syncthreads();
  for (int d = 1; d < 1024; d <<= 1) {
    unsigned u = (t >= d) ? sc[t - d] : 0;
    __syncthreads();
    sc[t] += u;
    __syncthreads();
  }
  unsigned ex = sc[t] - s;
  if (2 * t < NSCAN) bsum[2 * t] = ex;
  if (2 * t + 1 < NSCAN) bsum[2 * t + 1] = ex + a0;
}

__global__ __launch_bounds__(SCAN_TPB) void k_scanC(unsigned* __restrict__ h,
                                                    const unsigned* __restrict__ bsum) {
  unsigned add = bsum[blockIdx.x];
  size_t base = (size_t)blockIdx.x * SCAN_EPB + (size_t)threadIdx.x * 4;
  uint4 v = *(uint4*)(h + base);
  v.x += add; v.y += add; v.z += add; v.w += add;
  *(uint4*)(h + base) = v;
}

// Register-stash + LDS-reorder fill, SoA output: PK (u32) + W16 (bf16).
// pk = row<<12 | col&0xFFF; row < 2^20 fits.
// 1024 threads x 6 edges (CHUNK 6144 unchanged); ~47KB LDS -> 32 waves/CU.
__global__ __launch_bounds__(FBLK_F) void k_fill(const int* __restrict__ row,
                                                 const int* __restrict__ col,
                                                 const float* __restrict__ ew,
                                                 const unsigned* __restrict__ histT2,
                                                 unsigned* __restrict__ PK,
                                                 unsigned short* __restrict__ W16) {
  __shared__ unsigned lhist[256];
  __shared__ unsigned lb[256];
  __shared__ unsigned tail[256];
  __shared__ unsigned gbase[NB];
  __shared__ unsigned wsum[4];
  __shared__ unsigned spk[CHUNK];          // 24KB
  __shared__ unsigned short sw[CHUNK];     // 12KB
  __shared__ unsigned char sbkt[CHUNK];    // 6KB

  int t = threadIdx.x;
  int blk = blockIdx.x;
  if (t < 256) lhist[t] = 0;
  if (t < NB) gbase[t] = histT2[(size_t)blk * 256 + t];  // coalesced row read
  __syncthreads();                                        // B1

  int e0 = blk * CHUNK;
  unsigned pk[EPT_F];
  unsigned short wv[EPT_F];
  int bk[EPT_F];
  if (e0 + CHUNK <= N_EDGES) {          // fast path (2604 of 2605 blocks)
    int cv[EPT_F], rv[EPT_F];
    float wf[EPT_F];
#pragma unroll
    for (int k = 0; k < EPT_F; ++k) {
      int e = e0 + k * FBLK_F + t;
      cv[k] = col[e];
      rv[k] = row[e];
      wf[k] = ew[e];
    }
    __builtin_amdgcn_sched_barrier(0);  // 18 loads in flight before any use
#pragma unroll
    for (int k = 0; k < EPT_F; ++k) {
      pk[k] = ((unsigned)rv[k] << BSHIFT) | (unsigned)(cv[k] & (BNODES - 1));
      wv[k] = f2bf(wf[k]);
      bk[k] = cv[k] >> BSHIFT;
    }
#pragma unroll
    for (int k = 0; k < EPT_F; ++k) atomicAdd(&lhist[bk[k]], 1u);
  } else {
#pragma unroll
    for (int k = 0; k < EPT_F; ++k) {
      int e = e0 + k * FBLK_F + t;
      bk[k] = -1;
      if (e < N_EDGES) {
        int c = col[e];
        pk[k] = ((unsigned)row[e] << BSHIFT) | (unsigned)(c & (BNODES - 1));
        wv[k] = f2bf(ew[e]);
        bk[k] = c >> BSHIFT;
        atomicAdd(&lhist[bk[k]], 1u);
      }
    }
  }
  __syncthreads();                                        // B2

  // exclusive prefix over 256 bucket counts (threads 0-255 = 4 waves)
  unsigned own = 0, v = 0;
  if (t < 256) {
    own = lhist[t];
    v = own;
#pragma unroll
    for (int d = 1; d < 64; d <<= 1) {
      unsigned u = __shfl_up(v, d, 64);
      if ((t & 63) >= d) v += u;
    }
    if ((t & 63) == 63) wsum[t >> 6] = v;
  }
  __syncthreads();                                        // B3
  unsigned total = wsum[0] + wsum[1] + wsum[2] + wsum[3];
  if (t < 256) {
    unsigned wbase = 0;
#pragma unroll
    for (int w = 0; w < 4; ++w)
      if (w < (t >> 6)) wbase += wsum[w];
    unsigned ex = wbase + v - own;
    lb[t] = ex;
    tail[t] = ex;
  }
  __syncthreads();                                        // B4

  if (e0 + CHUNK <= N_EDGES) {
#pragma unroll
    for (int k = 0; k < EPT_F; ++k) {
      unsigned s = atomicAdd(&tail[bk[k]], 1u);
      spk[s] = pk[k];
      sw[s] = wv[k];
      sbkt[s] = (unsigned char)bk[k];
    }
  } else {
#pragma unroll
    for (int k = 0; k < EPT_F; ++k) {
      if (bk[k] >= 0) {
        unsigned s = atomicAdd(&tail[bk[k]], 1u);
        spk[s] = pk[k];
        sw[s] = wv[k];
        sbkt[s] = (unsigned char)bk[k];
      }
    }
  }
  __syncthreads();                                        // B5

  // staged order is bucket-sorted: consecutive s -> consecutive global dest.
  unsigned s = t;
  for (; s + 3u * FBLK_F < total; s += 4u * FBLK_F) {
#pragma unroll
    for (int u = 0; u < 4; ++u) {
      unsigned si = s + u * FBLK_F;
      unsigned b = sbkt[si];
      unsigned idx = gbase[b] + (si - lb[b]);
      PK[idx] = spk[si];
      W16[idx] = sw[si];
    }
  }
  for (; s < total; s += FBLK_F) {
    unsigned b = sbkt[s];
    unsigned idx = gbase[b] + (s - lb[b]);
    PK[idx] = spk[s];
    W16[idx] = sw[s];
  }
}

// ---------------- accumulate: one (bucket,part) per block ----------------
// mode 0: val = ew. mode 1: val = ew * bf16 p16[row].
// FIXED-POINT LDS accumulator (ds_add_u32 ~5x faster than ds_add_f32).
constexpr int ABLK = 512;

__global__ __launch_bounds__(ABLK) void k_acc(const unsigned* __restrict__ PK,
                                              const unsigned short* __restrict__ W16,
                                              const unsigned* __restrict__ hist,
                                              const unsigned short* __restrict__ p16,
                                              float* __restrict__ out,
                                              int mode, int split,
                                              float FS, float INV) {
  __shared__ int acc[BNODES];
  {
    int4* a4 = (int4*)acc;
#pragma unroll
    for (int i = threadIdx.x; i < BNODES / 4; i += ABLK)
      a4[i] = make_int4(0, 0, 0, 0);
  }
  __syncthreads();
  int b = blockIdx.x / split;
  int part = blockIdx.x - b * split;
  unsigned bs = hist[(size_t)b * NBLK];
  unsigned be = (b + 1 < NB) ? hist[(size_t)(b + 1) * NBLK] : (unsigned)N_EDGES;
  unsigned len = be - bs;
  unsigned s = bs + (unsigned)(((unsigned long long)len * part) / split);
  unsigned e = bs + (unsigned)(((unsigned long long)len * (part + 1)) / split);
  unsigned t = threadIdx.x;

  unsigned s_al = (s + 7u) & ~7u;        // align to 8 records
  if (s_al > e) s_al = e;
  if (t == 0) {                          // scalar head (<8 records)
    for (unsigned i = s; i < s_al; ++i) {
      unsigned pk = PK[i];
      float v = bf2f(W16[i]);
      if (mode) v *= bf2f(p16[pk >> BSHIFT]);
      atomicAdd(&acc[pk & (BNODES - 1)], __float2int_rn(v * FS));
    }
  }
  s = s_al;
  unsigned n = (e > s) ? (e - s) : 0u;
  unsigned ng = n >> 3;                  // groups of 8 records
  const uint4* pk4 = (const uint4*)(PK + s);    // group g: pk4[2g], pk4[2g+1]
  const uint4* w4  = (const uint4*)(W16 + s);   // group g: w4[g] (8 bf16)

  unsigned ip = t;
  for (; ip + ABLK < ng; ip += 2u * ABLK) {     // 2 groups = 16 records
    unsigned g1 = ip + ABLK;
    uint4 pA0 = pk4[2u * ip], pA1 = pk4[2u * ip + 1u];
    uint4 pB0 = pk4[2u * g1], pB1 = pk4[2u * g1 + 1u];
    uint4 wA = w4[ip], wB = w4[g1];
    __builtin_amdgcn_sched_barrier(0);   // 6 loads issued before any use
    if (mode) {
      unsigned short gA0 = p16[pA0.x >> BSHIFT], gA1 = p16[pA0.y >> BSHIFT];
      unsigned short gA2 = p16[pA0.z >> BSHIFT], gA3 = p16[pA0.w >> BSHIFT];
      unsigned short gA4 = p16[pA1.x >> BSHIFT], gA5 = p16[pA1.y >> BSHIFT];
      unsigned short gA6 = p16[pA1.z >> BSHIFT], gA7 = p16[pA1.w >> BSHIFT];
      unsigned short gB0 = p16[pB0.x >> BSHIFT], gB1 = p16[pB0.y >> BSHIFT];
      unsigned short gB2 = p16[pB0.z >> BSHIFT], gB3 = p16[pB0.w >> BSHIFT];
      unsigned short gB4 = p16[pB1.x >> BSHIFT], gB5 = p16[pB1.y >> BSHIFT];
      unsigned short gB6 = p16[pB1.z >> BSHIFT], gB7 = p16[pB1.w >> BSHIFT];
      __builtin_amdgcn_sched_barrier(0); // 16 gathers in flight before use
      atomicAdd(&acc[pA0.x & (BNODES - 1)], __float2int_rn(blo(wA.x) * bf2f(gA0) * FS));
      atomicAdd(&acc[pA0.y & (BNODES - 1)], __float2int_rn(bhi(wA.x) * bf2f(gA1) * FS));
      atomicAdd(&acc[pA0.z & (BNODES - 1)], __float2int_rn(blo(wA.y) * bf2f(gA2) * FS));
      atomicAdd(&acc[pA0.w & (BNODES - 1)], __float2int_rn(bhi(wA.y) * bf2f(gA3) * FS));
      atomicAdd(&acc[pA1.x & (BNODES - 1)], __float2int_rn(blo(wA.z) * bf2f(gA4) * FS));
      atomicAdd(&acc[pA1.y & (BNODES - 1)], __float2int_rn(bhi(wA.z) * bf2f(gA5) * FS));
      atomicAdd(&acc[pA1.z & (BNODES - 1)], __float2int_rn(blo(wA.w) * bf2f(gA6) * FS));
      atomicAdd(&acc[pA1.w & (BNODES - 1)], __float2int_rn(bhi(wA.w) * bf2f(gA7) * FS));
      atomicAdd(&acc[pB0.x & (BNODES - 1)], __float2int_rn(blo(wB.x) * bf2f(gB0) * FS));
      atomicAdd(&acc[pB0.y & (BNODES - 1)], __float2int_rn(bhi(wB.x) * bf2f(gB1) * FS));
      atomicAdd(&acc[pB0.z & (BNODES - 1)], __float2int_rn(blo(wB.y) * bf2f(gB2) * FS));
      atomicAdd(&acc[pB0.w & (BNODES - 1)], __float2int_rn(bhi(wB.y) * bf2f(gB3) * FS));
      atomicAdd(&acc[pB1.x & (BNODES - 1)], __float2int_rn(blo(wB.z) * bf2f(gB4) * FS));
      atomicAdd(&acc[pB1.y & (BNODES - 1)], __float2int_rn(bhi(wB.z) * bf2f(gB5) * FS));
      atomicAdd(&acc[pB1.z & (BNODES - 1)], __float2int_rn(blo(wB.w) * bf2f(gB6) * FS));
      atomicAdd(&acc[pB1.w & (BNODES - 1)], __float2int_rn(bhi(wB.w) * bf2f(gB7) * FS));
    } else {
      atomicAdd(&acc[pA0.x & (BNODES - 1)], __float2int_rn(blo(wA.x) * FS));
      atomicAdd(&acc[pA0.y & (BNODES - 1)], __float2int_rn(bhi(wA.x) * FS));
      atomicAdd(&acc[pA0.z & (BNODES - 1)], __float2int_rn(blo(wA.y) * FS));
      atomicAdd(&acc[pA0.w & (BNODES - 1)], __float2int_rn(bhi(wA.y) * FS));
      atomicAdd(&acc[pA1.x & (BNODES - 1)], __float2int_rn(blo(wA.z) * FS));
      atomicAdd(&acc[pA1.y & (BNODES - 1)], __float2int_rn(bhi(wA.z) * FS));
      atomicAdd(&acc[pA1.z & (BNODES - 1)], __float2int_rn(blo(wA.w) * FS));
      atomicAdd(&acc[pA1.w & (BNODES - 1)], __float2int_rn(bhi(wA.w) * FS));
      atomicAdd(&acc[pB0.x & (BNODES - 1)], __float2int_rn(blo(wB.x) * FS));
      atomicAdd(&acc[pB0.y & (BNODES - 1)], __float2int_rn(bhi(wB.x) * FS));
      atomicAdd(&acc[pB0.z & (BNODES - 1)], __float2int_rn(blo(wB.y) * FS));
      atomicAdd(&acc[pB0.w & (BNODES - 1)], __float2int_rn(bhi(wB.y) * FS));
      atomicAdd(&acc[pB1.x & (BNODES - 1)], __float2int_rn(blo(wB.z) * FS));
      atomicAdd(&acc[pB1.y & (BNODES - 1)], __float2int_rn(bhi(wB.z) * FS));
      atomicAdd(&acc[pB1.z & (BNODES - 1)], __float2int_rn(blo(wB.w) * FS));
      atomicAdd(&acc[pB1.w & (BNODES - 1)], __float2int_rn(bhi(wB.w) * FS));
    }
  }
  for (; ip < ng; ip += 2u * ABLK) {     // leftover single group (8 records)
    uint4 p0 = pk4[2u * ip], p1 = pk4[2u * ip + 1u];
    uint4 w = w4[ip];
    float v0 = blo(w.x), v1 = bhi(w.x), v2 = blo(w.y), v3 = bhi(w.y);
    float v4 = blo(w.z), v5 = bhi(w.z), v6 = blo(w.w), v7 = bhi(w.w);
    if (mode) {
      v0 *= bf2f(p16[p0.x >> BSHIFT]); v1 *= bf2f(p16[p0.y >> BSHIFT]);
      v2 *= bf2f(p16[p0.z >> BSHIFT]); v3 *= bf2f(p16[p0.w >> BSHIFT]);
      v4 *= bf2f(p16[p1.x >> BSHIFT]); v5 *= bf2f(p16[p1.y >> BSHIFT]);
      v6 *= bf2f(p16[p1.z >> BSHIFT]); v7 *= bf2f(p16[p1.w >> BSHIFT]);
    }
    atomicAdd(&acc[p0.x & (BNODES - 1)], __float2int_rn(v0 * FS));
    atomicAdd(&acc[p0.y & (BNODES - 1)], __float2int_rn(v1 * FS));
    atomicAdd(&acc[p0.z & (BNODES - 1)], __float2int_rn(v2 * FS));
    atomicAdd(&acc[p0.w & (BNODES - 1)], __float2int_rn(v3 * FS));
    atomicAdd(&acc[p1.x & (BNODES - 1)], __float2int_rn(v4 * FS));
    atomicAdd(&acc[p1.y & (BNODES - 1)], __float2int_rn(v5 * FS));
    atomicAdd(&acc[p1.z & (BNODES - 1)], __float2int_rn(v6 * FS));
    atomicAdd(&acc[p1.w & (BNODES - 1)], __float2int_rn(v7 * FS));
  }
  unsigned rem = n & 7u;                 // scalar tail, threads 0..rem-1
  if (t < rem) {
    unsigned i = s + (n - rem) + t;
    unsigned pk = PK[i];
    float v = bf2f(W16[i]);
    if (mode) v *= bf2f(p16[pk >> BSHIFT]);
    atomicAdd(&acc[pk & (BNODES - 1)], __float2int_rn(v * FS));
  }
  __syncthreads();

  float* o = out + (size_t)part * N_NODES;
  int base = b * BNODES;
  if (base + BNODES <= N_NODES) {        // full bucket: float4 writeout
    float4* o4 = (float4*)(o + base);
    const int4* a4 = (const int4*)acc;
#pragma unroll
    for (int j = threadIdx.x; j < BNODES / 4; j += ABLK) {
      int4 q = a4[j];
      o4[j] = make_float4((float)q.x * INV, (float)q.y * INV,
                          (float)q.z * INV, (float)q.w * INV);
    }
  } else {
    for (int j = threadIdx.x; base + j < N_NODES; j += ABLK)
      o[base + j] = (float)acc[j] * INV;
  }
}

// ---------------- node-wise kernels ----------------

__global__ void k_dis_p(const float* __restrict__ x, const float* __restrict__ D,
                        float* __restrict__ A, unsigned short* __restrict__ P16,
                        int split) {
  int i = blockIdx.x * blockDim.x + threadIdx.x;
  if (i >= N_NODES) return;
  float deg = 1.0f;                       // self loop
  for (int j = 0; j < split; ++j) deg += D[(size_t)j * N_NODES + i];
  float d = rsqrtf(deg);
  A[i] = d;
  P16[i] = f2bf(d * x[i]);
}

__global__ void k_g2(const float* __restrict__ A, const float* __restrict__ x,
                     const float* __restrict__ D, unsigned short* __restrict__ P16,
                     const float* __restrict__ W1, const float* __restrict__ b1,
                     const float* __restrict__ W2, int split) {
  int i = blockIdx.x * blockDim.x + threadIdx.x;
  if (i >= N_NODES) return;
  float d = A[i];
  float sraw = 0.f;
  for (int j = 0; j < split; ++j) sraw += D[(size_t)j * N_NODES + i];
  float s1 = d * sraw + d * d * x[i];
  float g = 0.f;
#pragma unroll
  for (int j = 0; j < 4; ++j) {
    float h = fmaf(s1, W1[j], b1[j]);
    g = fmaf(fmaxf(h, 0.f), W2[j], g);
  }
  P16[i] = f2bf(d * g);
}

__global__ void k_out2(const float* __restrict__ A,
                       const unsigned short* __restrict__ P16,
                       const float* __restrict__ D, const float* __restrict__ b2,
                       const float* __restrict__ Wl, const float* __restrict__ bl,
                       float* __restrict__ y, int split) {
  int i = blockIdx.x * blockDim.x + threadIdx.x;
  if (i >= N_NODES) return;
  float d = A[i];
  float g = bf2f(P16[i]) / d;             // d in (0,1], safe
  float sraw = 0.f;
  for (int j = 0; j < split; ++j) sraw += D[(size_t)j * N_NODES + i];
  float agg2 = d * sraw + d * d * g;
  float v = fmaf(agg2 + b2[0], Wl[0], bl[0]);
  y[i] = 1.0f / (1.0f + expf(-v));
}

// ---------------- fallback (round-2 global-atomic path) ----------------

__global__ void f_deg(const int* __restrict__ col, const float* __restrict__ ew,
                      float* __restrict__ deg) {
  int i = blockIdx.x * blockDim.x + threadIdx.x;
  int stride = gridDim.x * blockDim.x;
  for (int e = i; e < N_EDGES; e += stride) atomicAdd(&deg[col[e]], ew[e]);
}
__global__ void f_dis(float* __restrict__ a) {
  int i = blockIdx.x * blockDim.x + threadIdx.x;
  if (i < N_NODES) a[i] = rsqrtf(a[i] + 1.0f);
}
__global__ void f_scatter(const int* __restrict__ row, const int* __restrict__ col,
                          const float* __restrict__ ew, const float* __restrict__ dis,
                          const float* __restrict__ src, float* __restrict__ acc) {
  int i = blockIdx.x * blockDim.x + threadIdx.x;
  int stride = gridDim.x * blockDim.x;
  for (int e = i; e < N_EDGES; e += stride) {
    int r = row[e]; int c = col[e];
    atomicAdd(&acc[c], dis[r] * ew[e] * src[r]);
  }
}
__global__ void f_g(const float* __restrict__ dis, const float* __restrict__ x,
                    float* __restrict__ s1g, const float* __restrict__ W1,
                    const float* __restrict__ b1, const float* __restrict__ W2) {
  int i = blockIdx.x * blockDim.x + threadIdx.x;
  if (i >= N_NODES) return;
  float d = dis[i];
  float s1 = d * s1g[i] + d * d * x[i];
  float g = 0.f;
#pragma unroll
  for (int j = 0; j < 4; ++j) {
    float h = fmaf(s1, W1[j], b1[j]);
    g = fmaf(fmaxf(h, 0.f), W2[j], g);
  }
  s1g[i] = g;
}
__global__ void f_out(const float* __restrict__ dis, const float* __restrict__ g,
                      float* __restrict__ s2out, const float* __restrict__ b2,
                      const float* __restrict__ Wl, const float* __restrict__ bl) {
  int i = blockIdx.x * blockDim.x + threadIdx.x;
  if (i >= N_NODES) return;
  float d = dis[i];
  float agg2 = d * s2out[i] + d * d * g[i];
  float v = fmaf(agg2 + b2[0], Wl[0], bl[0]);
  s2out[i] = 1.0f / (1.0f + expf(-v));
}

// ---------------- launch ----------------

extern "C" void kernel_launch(void* const* d_in, const int* in_sizes, int n_in,
                              void* d_out, int out_size, void* d_ws, size_t ws_size,
                              hipStream_t stream) {
  const float* x  = (const float*)d_in[0];
  const int* ei   = (const int*)d_in[1];   // int32 (harness narrows int64)
  const float* ew = (const float*)d_in[2];
  const float* W1 = (const float*)d_in[3];
  const float* b1 = (const float*)d_in[4];
  const float* W2 = (const float*)d_in[5];
  const float* b2 = (const float*)d_in[6];
  const float* Wl = (const float*)d_in[7];
  const float* bl = (const float*)d_in[8];

  const int* row = ei;
  const int* col = ei + N_EDGES;

  auto pad = [](size_t v) { return (v + 255) & ~(size_t)255; };
  const size_t PK_B    = pad((size_t)N_EDGES * 4);         // 64,000,000
  const size_t W16_B   = pad((size_t)N_EDGES * 2);         // 32,000,000
  const size_t HIST_B  = pad((size_t)NHIST_PAD * 4);       // 2,555,904
  const size_t HISTT_B = pad((size_t)NBLK * 256 * 4);      // 2,667,520
  const size_t BSUM_B  = 8192;
  const size_t NODE_B  = pad((size_t)N_NODES * 4);
  const size_t P16_B   = pad((size_t)N_NODES * 2);
  const size_t BASE    = PK_B + W16_B + HIST_B + HISTT_B + BSUM_B + NODE_B + P16_B;

  dim3 blk(256);
  dim3 ngrid((N_NODES + 255) / 256);
  dim3 tgrid((NBLK + 31) / 32, 8);
  dim3 tblk(32, 32);

  // fixed-point scales: deg <= 64 -> 2^22 (max 2^28); s1/s2 worst |sum| ~2e5
  // -> 2^12 (range +-2^19 after sum; resolution 2.4e-4 << absmax margin)
  const float FS0 = 4194304.f, INV0 = 1.f / 4194304.f;
  const float FS1 = 4096.f,    INV1 = 1.f / 4096.f;

  int split = 0;
  for (int s : {4, 2, 1})
    if (ws_size >= BASE + (size_t)s * NODE_B) { split = s; break; }

  if (split) {
    char* w = (char*)d_ws;
    unsigned* PK        = (unsigned*)w;
    unsigned short* W16 = (unsigned short*)(w + PK_B);
    unsigned* hist      = (unsigned*)(w + PK_B + W16_B);
    unsigned* histT     = (unsigned*)(w + PK_B + W16_B + HIST_B);  // also histT2
    unsigned* bsum      = (unsigned*)(w + PK_B + W16_B + HIST_B + HISTT_B);
    float* A            = (float*)(w + PK_B + W16_B + HIST_B + HISTT_B + BSUM_B);
    unsigned short* P16 = (unsigned short*)((char*)A + NODE_B);
    float* D            = (float*)((char*)P16 + P16_B);    // split partials

    // zero the scan pad tail (rest of hist fully written by k_t1)
    hipMemsetAsync(hist + NHIST, 0, (size_t)(NHIST_PAD - NHIST) * 4, stream);

    k_count<<<NBLK, FBLK_C, 0, stream>>>(col, histT);
    k_t1   <<<tgrid, tblk, 0, stream>>>(histT, hist);
    k_scanA<<<NSCAN, SCAN_TPB, 0, stream>>>(hist, bsum);
    k_scanB<<<1, 1024, 0, stream>>>(bsum);
    k_scanC<<<NSCAN, SCAN_TPB, 0, stream>>>(hist, bsum);
    k_t2   <<<tgrid, tblk, 0, stream>>>(hist, histT);      // offsets, transposed
    k_fill <<<NBLK, FBLK_F, 0, stream>>>(row, col, ew, histT, PK, W16);

    k_acc  <<<NB * split, ABLK, 0, stream>>>(PK, W16, hist, nullptr, D, 0, split, FS0, INV0);
    k_dis_p<<<ngrid, blk, 0, stream>>>(x, D, A, P16, split);
    k_acc  <<<NB * split, ABLK, 0, stream>>>(PK, W16, hist, P16, D, 1, split, FS1, INV1);
    k_g2   <<<ngrid, blk, 0, stream>>>(A, x, D, P16, W1, b1, W2, split);
    k_acc  <<<NB * split, ABLK, 0, stream>>>(PK, W16, hist, P16, D, 1, split, FS1, INV1);
    k_out2 <<<ngrid, blk, 0, stream>>>(A, P16, D, b2, Wl, bl, (float*)d_out, split);
  } else {
    float* Aw = (float*)d_ws;
    float* Bw = Aw + N_NODES;
    float* Cw = (float*)d_out;
    hipMemsetAsync(d_ws, 0, 2ull * N_NODES * 4, stream);
    hipMemsetAsync(d_out, 0, (size_t)N_NODES * 4, stream);
    dim3 egrid(4096);
    f_deg<<<egrid, blk, 0, stream>>>(col, ew, Aw);
    f_dis<<<ngrid, blk, 0, stream>>>(Aw);
    f_scatter<<<egrid, blk, 0, stream>>>(row, col, ew, Aw, x, Bw);
    f_g<<<ngrid, blk, 0, stream>>>(Aw, x, Bw, W1, b1, W2);
    f_scatter<<<egrid, blk, 0, stream>>>(row, col, ew, Aw, Bw, Cw);
    f_out<<<ngrid, blk, 0, stream>>>(Aw, Bw, Cw, b2, Wl, bl);
  }
}